// Round 6
// baseline (257.685 us; speedup 1.0000x reference)
//
#include <hip/hip_runtime.h>
#include <hip/hip_bf16.h>
#include <stdint.h>

// ---------------- types / helpers ----------------
typedef __bf16 bf16x8 __attribute__((ext_vector_type(8)));
typedef unsigned short u16x8 __attribute__((ext_vector_type(8)));
typedef float f32x4 __attribute__((ext_vector_type(4)));
typedef float f32x16 __attribute__((ext_vector_type(16)));
typedef uint32_t u32x4 __attribute__((ext_vector_type(4)));

#define DMODEL 768
#define NSEQ   2048
#define BATCH  2
#define NHEAD  12
#define HDIM   64
#define HIDDEN 3072

__device__ __forceinline__ uint16_t f2bf(float f) {
  __hip_bfloat16 h = __float2bfloat16(f);
  return __builtin_bit_cast(uint16_t, h);
}
__device__ __forceinline__ bf16x8 ldb8(const uint16_t* p) {
  return __builtin_bit_cast(bf16x8, *reinterpret_cast<const u16x8*>(p));
}

using as1_void = __attribute__((address_space(1))) const void;
using as3_void = __attribute__((address_space(3))) void;
__device__ __forceinline__ void gload16(const uint16_t* src, uint16_t* lds) {
  __builtin_amdgcn_global_load_lds((as1_void*)src, (as3_void*)lds, 16, 0, 0);
}
#define MEMFENCE asm volatile("" ::: "memory")

// ---------------- fused fp32 -> bf16 casts ----------------
#define N_QKVW  (3 * DMODEL * DMODEL)
#define N_PROJW (DMODEL * DMODEL)
#define N_FC1W  (HIDDEN * DMODEL)
#define N_FC2W  (DMODEL * HIDDEN)
__global__ __launch_bounds__(256) void cvt4_kernel(const float* __restrict__ s0,
                                                   const float* __restrict__ s1,
                                                   const float* __restrict__ s2,
                                                   const float* __restrict__ s3,
                                                   uint16_t* __restrict__ d0,
                                                   uint16_t* __restrict__ d1,
                                                   uint16_t* __restrict__ d2,
                                                   uint16_t* __restrict__ d3) {
  int i4 = (blockIdx.x * 256 + threadIdx.x) * 4;
  const float* s;
  uint16_t* d;
  if (i4 < N_QKVW) { s = s0 + i4; d = d0 + i4; }
  else if (i4 < N_QKVW + N_PROJW) { int j = i4 - N_QKVW; s = s1 + j; d = d1 + j; }
  else if (i4 < N_QKVW + N_PROJW + N_FC1W) { int j = i4 - N_QKVW - N_PROJW; s = s2 + j; d = d2 + j; }
  else { int j = i4 - N_QKVW - N_PROJW - N_FC1W; s = s3 + j; d = d3 + j; }
  float4 v = *reinterpret_cast<const float4*>(s);
  ushort4 o;
  o.x = f2bf(v.x); o.y = f2bf(v.y); o.z = f2bf(v.z); o.w = f2bf(v.w);
  *reinterpret_cast<ushort4*>(d) = o;
}

// ---------------- qkv bias assembly ----------------
__global__ __launch_bounds__(256) void bias_kernel(const float* __restrict__ qb,
                                                   const float* __restrict__ vb,
                                                   float* __restrict__ out) {
  int j = blockIdx.x * 256 + threadIdx.x;
  if (j < 3 * DMODEL) {
    float v = 0.f;
    if (j < DMODEL) v = qb[j];
    else if (j >= 2 * DMODEL) v = vb[j - 2 * DMODEL];
    out[j] = v;
  }
}

// ---------------- layernorm: fp32 in -> bf16 out ----------------
__global__ __launch_bounds__(256) void ln_kernel(const float* __restrict__ x,
                                                 const float* __restrict__ g,
                                                 const float* __restrict__ bt,
                                                 uint16_t* __restrict__ out) {
  const int row = blockIdx.x;
  const int t = threadIdx.x;
  const float* xr = x + (size_t)row * DMODEL;
  float v0 = xr[t], v1 = xr[t + 256], v2 = xr[t + 512];
  float s = v0 + v1 + v2;
  float q = v0 * v0 + v1 * v1 + v2 * v2;
  for (int off = 32; off >= 1; off >>= 1) {
    s += __shfl_xor(s, off);
    q += __shfl_xor(q, off);
  }
  __shared__ float ss[4], sq[4];
  int w = t >> 6;
  if ((t & 63) == 0) { ss[w] = s; sq[w] = q; }
  __syncthreads();
  s = ss[0] + ss[1] + ss[2] + ss[3];
  q = sq[0] + sq[1] + sq[2] + sq[3];
  const float mean = s * (1.0f / DMODEL);
  const float var = q * (1.0f / DMODEL) - mean * mean;
  const float rstd = rsqrtf(var + 1e-5f);
  uint16_t* orow = out + (size_t)row * DMODEL;
  orow[t]       = f2bf((v0 - mean) * rstd * g[t]       + bt[t]);
  orow[t + 256] = f2bf((v1 - mean) * rstd * g[t + 256] + bt[t + 256]);
  orow[t + 512] = f2bf((v2 - mean) * rstd * g[t + 512] + bt[t + 512]);
}

// ------------- GEMM A: 128x128 block, 4 waves x (64x64), dbuf counted-vmcnt ----
template <int MODE>
__global__ __launch_bounds__(256, 3) void gemm128(const uint16_t* __restrict__ A,
                                                  const uint16_t* __restrict__ W,
                                                  const float* __restrict__ bias,
                                                  void* __restrict__ outp,
                                                  int M, int N, int K) {
  __shared__ uint16_t As[2][128 * 32];
  __shared__ uint16_t Bs[2][128 * 32];
  const int tid = threadIdx.x;
  const int lane = tid & 63;
  const int w = tid >> 6;
  const int wr = w >> 1, wc = w & 1;
  const int row0 = blockIdx.y * 128;
  const int col0 = blockIdx.x * 128;
  const int lr = lane & 15;
  const int g = lane >> 4;

  const int o0 = w * 1024 + lane * 16;
  const int o1 = o0 + 4096;
  const int r0s = o0 >> 6, c0s = (o0 & 63) >> 1;
  const int r1s = o1 >> 6, c1s = (o1 & 63) >> 1;
  const int l0 = (w * 1024) >> 1;
  const int l1 = l0 + 2048;
  const uint16_t* Abase = A + (size_t)row0 * K;
  const uint16_t* Wbase = W + (size_t)col0 * K;

  auto stage = [&](int kt) {
    uint16_t* Ad = &As[kt & 1][0];
    uint16_t* Bd = &Bs[kt & 1][0];
    const int kk = kt * 32;
    gload16(Abase + (size_t)r0s * K + kk + c0s, Ad + l0);
    gload16(Abase + (size_t)r1s * K + kk + c1s, Ad + l1);
    gload16(Wbase + (size_t)r0s * K + kk + c0s, Bd + l0);
    gload16(Wbase + (size_t)r1s * K + kk + c1s, Bd + l1);
  };

  f32x4 acc[4][4] = {};
  const int nt = K >> 5;
  stage(0);
  for (int kt = 0; kt < nt; ++kt) {
    if (kt + 1 < nt) {
      stage(kt + 1);
      asm volatile("s_waitcnt vmcnt(4)" ::: "memory");
    } else {
      asm volatile("s_waitcnt vmcnt(0)" ::: "memory");
    }
    __builtin_amdgcn_s_barrier();
    MEMFENCE;
    const uint16_t* Ab = &As[kt & 1][0];
    const uint16_t* Bb = &Bs[kt & 1][0];
    bf16x8 a[4], b[4];
#pragma unroll
    for (int m = 0; m < 4; ++m) a[m] = ldb8(Ab + (wr * 64 + m * 16 + lr) * 32 + g * 8);
#pragma unroll
    for (int n = 0; n < 4; ++n) b[n] = ldb8(Bb + (wc * 64 + n * 16 + lr) * 32 + g * 8);
#pragma unroll
    for (int m = 0; m < 4; ++m)
#pragma unroll
      for (int n = 0; n < 4; ++n)
        acc[m][n] = __builtin_amdgcn_mfma_f32_16x16x32_bf16(a[m], b[n], acc[m][n], 0, 0, 0);
    MEMFENCE;
    __builtin_amdgcn_s_barrier();
  }

#pragma unroll
  for (int m = 0; m < 4; ++m) {
    int row = row0 + wr * 64 + m * 16 + g * 4;
#pragma unroll
    for (int n = 0; n < 4; ++n) {
      int col = col0 + wc * 64 + n * 16 + lr;
      float bv = bias[col];
#pragma unroll
      for (int ri = 0; ri < 4; ++ri) {
        float val = acc[m][n][ri] + bv;
        size_t idx = (size_t)(row + ri) * N + col;
        if constexpr (MODE == 0) {
          if (col < DMODEL) val *= 0.125f;
          ((uint16_t*)outp)[idx] = f2bf(val);
        } else {
          float ge = 0.5f * val * (1.0f + erff(val * 0.70710678118654752f));
          ((uint16_t*)outp)[idx] = f2bf(ge);
        }
      }
    }
  }
}

// ------------- GEMM B: 128x64 block (for N=768 shapes -> 384 blocks) -----------
__global__ __launch_bounds__(256, 3) void gemm64(const uint16_t* __restrict__ A,
                                                 const uint16_t* __restrict__ W,
                                                 const float* __restrict__ bias,
                                                 float* __restrict__ outp,
                                                 const float* __restrict__ resid,
                                                 const float* __restrict__ gamma,
                                                 int M, int N, int K) {
  __shared__ uint16_t As[2][128 * 32];
  __shared__ uint16_t Bs[2][64 * 32];
  const int tid = threadIdx.x;
  const int lane = tid & 63;
  const int w = tid >> 6;
  const int wr = w >> 1, wc = w & 1;
  const int row0 = blockIdx.y * 128;
  const int col0 = blockIdx.x * 64;
  const int lr = lane & 15;
  const int g = lane >> 4;

  const int o0 = w * 1024 + lane * 16;
  const int o1 = o0 + 4096;
  const int r0s = o0 >> 6, c0s = (o0 & 63) >> 1;
  const int r1s = o1 >> 6, c1s = (o1 & 63) >> 1;
  const int l0 = (w * 1024) >> 1;
  const int l1 = l0 + 2048;
  const uint16_t* Abase = A + (size_t)row0 * K;
  const uint16_t* Wbase = W + (size_t)col0 * K;

  auto stage = [&](int kt) {
    uint16_t* Ad = &As[kt & 1][0];
    uint16_t* Bd = &Bs[kt & 1][0];
    const int kk = kt * 32;
    gload16(Abase + (size_t)r0s * K + kk + c0s, Ad + l0);
    gload16(Abase + (size_t)r1s * K + kk + c1s, Ad + l1);
    gload16(Wbase + (size_t)r0s * K + kk + c0s, Bd + l0);
  };

  f32x4 acc[4][2] = {};
  const int nt = K >> 5;
  stage(0);
  for (int kt = 0; kt < nt; ++kt) {
    if (kt + 1 < nt) {
      stage(kt + 1);
      asm volatile("s_waitcnt vmcnt(3)" ::: "memory");
    } else {
      asm volatile("s_waitcnt vmcnt(0)" ::: "memory");
    }
    __builtin_amdgcn_s_barrier();
    MEMFENCE;
    const uint16_t* Ab = &As[kt & 1][0];
    const uint16_t* Bb = &Bs[kt & 1][0];
    bf16x8 a[4], b[2];
#pragma unroll
    for (int m = 0; m < 4; ++m) a[m] = ldb8(Ab + (wr * 64 + m * 16 + lr) * 32 + g * 8);
#pragma unroll
    for (int n = 0; n < 2; ++n) b[n] = ldb8(Bb + (wc * 32 + n * 16 + lr) * 32 + g * 8);
#pragma unroll
    for (int m = 0; m < 4; ++m)
#pragma unroll
      for (int n = 0; n < 2; ++n)
        acc[m][n] = __builtin_amdgcn_mfma_f32_16x16x32_bf16(a[m], b[n], acc[m][n], 0, 0, 0);
    MEMFENCE;
    __builtin_amdgcn_s_barrier();
  }

#pragma unroll
  for (int m = 0; m < 4; ++m) {
    int row = row0 + wr * 64 + m * 16 + g * 4;
#pragma unroll
    for (int n = 0; n < 2; ++n) {
      int col = col0 + wc * 32 + n * 16 + lr;
      float bv = bias[col];
      float gv = gamma[col];
#pragma unroll
      for (int ri = 0; ri < 4; ++ri) {
        float val = acc[m][n][ri] + bv;
        size_t idx = (size_t)(row + ri) * N + col;
        outp[idx] = resid[idx] + gv * val;
      }
    }
  }
}

// ---------------- V transpose (LDS-tiled, coalesced): qkv -> vt[bh][d][n] ------
__global__ __launch_bounds__(256) void vtrans_kernel(const uint16_t* __restrict__ qkv,
                                                     uint16_t* __restrict__ vt) {
  __shared__ uint16_t tile[64][72];
  const int t = threadIdx.x;
  const int bh = blockIdx.x;
  const int n0 = blockIdx.y * 64;
  const int b = bh / NHEAD, h = bh % NHEAD;
  const uint16_t* src = qkv + (size_t)(b * NSEQ + n0) * (3 * DMODEL) + 2 * DMODEL + h * HDIM;
#pragma unroll
  for (int it = 0; it < 2; ++it) {
    int slot = it * 256 + t;
    int r = slot >> 2, c = (slot & 3) * 16;
    u16x8 v0 = *reinterpret_cast<const u16x8*>(src + (size_t)r * (3 * DMODEL) + c);
    u16x8 v1 = *reinterpret_cast<const u16x8*>(src + (size_t)r * (3 * DMODEL) + c + 8);
    *reinterpret_cast<u16x8*>(&tile[r][c]) = v0;
    *reinterpret_cast<u16x8*>(&tile[r][c + 8]) = v1;
  }
  __syncthreads();
  uint16_t* dst = vt + (size_t)bh * HDIM * NSEQ + n0;
#pragma unroll
  for (int it = 0; it < 2; ++it) {
    int slot = it * 256 + t;
    int d = slot >> 2, c = (slot & 3) * 16;
    u16x8 a0, a1;
#pragma unroll
    for (int e = 0; e < 8; ++e) a0[e] = tile[c + e][d];
#pragma unroll
    for (int e = 0; e < 8; ++e) a1[e] = tile[c + 8 + e][d];
    *reinterpret_cast<u16x8*>(dst + (size_t)d * NSEQ + c) = a0;
    *reinterpret_cast<u16x8*>(dst + (size_t)d * NSEQ + c + 8) = a1;
  }
}

// ---------------- flash attention v4: swapped-QK 32x32, in-register softmax ----
// 2 waves x 32 q-rows, grid (24,32)=768 blocks (3/CU). S^T = mfma(K,Q): lane owns
// q = lane&31, 32 of 64 k -> in-lane max/sum + 1 shfl_xor(32). P packed to bf16
// in-register; PV A-frag built with 8 shfl_xor(32) + cndmask (no P-LDS trip).
__global__ __launch_bounds__(128) void attn_kernel(const uint16_t* __restrict__ qkv,
                                                   const uint16_t* __restrict__ vt,
                                                   const int* __restrict__ mask,
                                                   uint16_t* __restrict__ o) {
  __shared__ uint16_t Kb[2][64 * 64];
  __shared__ uint16_t Vb[2][64 * 64];
  __shared__ unsigned long long mbits[NSEQ / 64];
  const int tid = threadIdx.x;
  const int lane = tid & 63;
  const int w = tid >> 6;            // 2 waves
  const int bh = blockIdx.x;
  const int b = bh / NHEAD, hd = bh % NHEAD;
  const int q0 = blockIdx.y * 64 + w * 32;
  const int l31 = lane & 31;
  const int hh = lane >> 5;          // half-wave id

  // mask -> one 64-bit word per KV tile
  const int* mb = mask + b * NSEQ;
#pragma unroll
  for (int it = 0; it < NSEQ / 128; ++it) {
    unsigned long long bm = __ballot(mb[it * 128 + tid] != 0);
    if (lane == 0) mbits[it * 2 + w] = bm;
  }

  // Q-frags (B-operand): row=q=lane&31, k-slot = hh*8+e, d-block = dblk*16
  bf16x8 qa[4];
  const uint16_t* qptr = qkv + (size_t)(b * NSEQ + q0 + l31) * (3 * DMODEL) + hd * HDIM + hh * 8;
#pragma unroll
  for (int dblk = 0; dblk < 4; ++dblk) qa[dblk] = ldb8(qptr + dblk * 16);

  const uint16_t* kglob = qkv + (size_t)b * NSEQ * (3 * DMODEL) + DMODEL + hd * HDIM;
  const uint16_t* vtb = vt + (size_t)bh * HDIM * NSEQ;

  __syncthreads();   // mbits visible before staging loop

  const int srow = tid >> 3;                      // 0..15
  const int sxor = ((tid & 7) ^ (srow & 7)) * 8;  // pre-swizzled source chunk
  auto stage = [&](int t) {
    const int pb = t & 1;
    const int k0 = t * 64;
#pragma unroll
    for (int i = 0; i < 4; ++i) {
      gload16(kglob + (size_t)(k0 + i * 16 + srow) * (3 * DMODEL) + sxor, &Kb[pb][i * 1024 + w * 512]);
      gload16(vtb + (size_t)(i * 16 + srow) * NSEQ + k0 + sxor, &Vb[pb][i * 1024 + w * 512]);
    }
  };

  float m_ = -1e30f, lsum = 0.f;
  f32x16 oacc[2] = {};

  stage(0);
  const int NT = NSEQ / 64;
  for (int t = 0; t < NT; ++t) {
    if (t + 1 < NT) {
      stage(t + 1);
      asm volatile("s_waitcnt vmcnt(8)" ::: "memory");
    } else {
      asm volatile("s_waitcnt vmcnt(0)" ::: "memory");
    }
    __builtin_amdgcn_s_barrier();
    MEMFENCE;
    const uint16_t* Kbp = &Kb[t & 1][0];
    const uint16_t* Vbp = &Vb[t & 1][0];

    // S^T[k][q] = mfma(K-frag, Q-frag)
    f32x16 st[2];
    __builtin_amdgcn_s_setprio(1);
#pragma unroll
    for (int kblk = 0; kblk < 2; ++kblk) {
      f32x16 acc = {};
      const uint16_t* kr = Kbp + (kblk * 32 + l31) * 64;
#pragma unroll
      for (int dblk = 0; dblk < 4; ++dblk) {
        bf16x8 kf = ldb8(kr + ((dblk * 2 + hh) ^ (l31 & 7)) * 8);
        acc = __builtin_amdgcn_mfma_f32_32x32x16_bf16(kf, qa[dblk], acc, 0, 0, 0);
      }
      st[kblk] = acc;
    }
    __builtin_amdgcn_s_setprio(0);

    const unsigned long long wb = mbits[t];
    const uint32_t wm0 = (uint32_t)wb, wm1 = (uint32_t)(wb >> 32);
    float p[32];
    float tm = -1e30f;
#pragma unroll
    for (int kblk = 0; kblk < 2; ++kblk) {
      const uint32_t wm = kblk ? wm1 : wm0;
#pragma unroll
      for (int r = 0; r < 16; ++r) {
        const int idx = (r & 3) + 8 * (r >> 2) + 4 * hh;   // k-local within 32-block
        float sv = st[kblk][r] + (((wm >> idx) & 1) ? 0.f : -3e30f);
        p[kblk * 16 + r] = sv;
        tm = fmaxf(tm, sv);
      }
    }
    tm = fmaxf(tm, __shfl_xor(tm, 32));
    if (__any(tm - m_ > 8.0f)) {        // defer-max (T13)
      float mn = fmaxf(m_, tm);
      float al = __expf(m_ - mn);
      lsum *= al;
      m_ = mn;
      float ar[16];
#pragma unroll
      for (int r = 0; r < 16; ++r)
        ar[r] = __shfl(al, (r & 3) + 8 * (r >> 2) + 4 * hh);
#pragma unroll
      for (int dblk = 0; dblk < 2; ++dblk)
#pragma unroll
        for (int r = 0; r < 16; ++r) oacc[dblk][r] *= ar[r];
    }
    float ls = 0.f;
    uint32_t pk[2][8];
#pragma unroll
    for (int kblk = 0; kblk < 2; ++kblk)
#pragma unroll
      for (int wn = 0; wn < 8; ++wn) {
        float e0 = __expf(p[kblk * 16 + 2 * wn] - m_);
        float e1 = __expf(p[kblk * 16 + 2 * wn + 1] - m_);
        ls += e0 + e1;
        pk[kblk][wn] = (uint32_t)f2bf(e0) | ((uint32_t)f2bf(e1) << 16);
      }
    ls += __shfl_xor(ls, 32);
    lsum += ls;

    // gather PV A-frags: af[kb16] covers k = kb16*16 + hh*8 + e for q = lane&31
    bf16x8 af[4];
#pragma unroll
    for (int kb16 = 0; kb16 < 4; ++kb16) {
      const int kblk = kb16 >> 1;
      const int a4 = (kb16 & 1) * 4;
      uint32_t ow0 = hh ? pk[kblk][a4 + 2] : pk[kblk][a4 + 0];
      uint32_t ow1 = hh ? pk[kblk][a4 + 3] : pk[kblk][a4 + 1];
      uint32_t gv0 = hh ? pk[kblk][a4 + 0] : pk[kblk][a4 + 2];
      uint32_t gv1 = hh ? pk[kblk][a4 + 1] : pk[kblk][a4 + 3];
      uint32_t sw0 = (uint32_t)__shfl_xor((int)gv0, 32);
      uint32_t sw1 = (uint32_t)__shfl_xor((int)gv1, 32);
      u32x4 afu;
      afu[0] = hh ? sw0 : ow0;
      afu[1] = hh ? sw1 : ow1;
      afu[2] = hh ? ow0 : sw0;
      afu[3] = hh ? ow1 : sw1;
      af[kb16] = __builtin_bit_cast(bf16x8, afu);
    }

    // PV: oacc[dblk] += P * V
    __builtin_amdgcn_s_setprio(1);
#pragma unroll
    for (int dblk = 0; dblk < 2; ++dblk) {
      const uint16_t* vr = Vbp + (dblk * 32 + l31) * 64;
#pragma unroll
      for (int kb16 = 0; kb16 < 4; ++kb16) {
        bf16x8 vf = ldb8(vr + ((kb16 * 2 + hh) ^ (l31 & 7)) * 8);
        oacc[dblk] = __builtin_amdgcn_mfma_f32_32x32x16_bf16(af[kb16], vf, oacc[dblk], 0, 0, 0);
      }
    }
    __builtin_amdgcn_s_setprio(0);
    MEMFENCE;
    __builtin_amdgcn_s_barrier();
  }

  float linv = lsum > 0.f ? 1.f / lsum : 0.f;
  uint16_t* ob = o + (size_t)(b * NSEQ + q0) * DMODEL + hd * HDIM;
#pragma unroll
  for (int r = 0; r < 16; ++r) {
    const int qrow = (r & 3) + 8 * (r >> 2) + 4 * hh;
    float iv = __shfl(linv, qrow);
#pragma unroll
    for (int dblk = 0; dblk < 2; ++dblk)
      ob[(size_t)qrow * DMODEL + dblk * 32 + l31] = f2bf(oacc[dblk][r] * iv);
  }
}

// ---------------- host ----------------
extern "C" void kernel_launch(void* const* d_in, const int* in_sizes, int n_in,
                              void* d_out, int out_size, void* d_ws, size_t ws_size,
                              hipStream_t stream) {
  const float* x      = (const float*)d_in[0];
  const int*   amask  = (const int*)d_in[1];
  const float* ln1_g  = (const float*)d_in[2];
  const float* ln1_b  = (const float*)d_in[3];
  const float* qkv_w  = (const float*)d_in[4];
  const float* q_bias = (const float*)d_in[5];
  const float* v_bias = (const float*)d_in[6];
  const float* proj_w = (const float*)d_in[7];
  const float* proj_b = (const float*)d_in[8];
  const float* ln2_g  = (const float*)d_in[9];
  const float* ln2_b  = (const float*)d_in[10];
  const float* fc1_w  = (const float*)d_in[11];
  const float* fc1_b  = (const float*)d_in[12];
  const float* fc2_w  = (const float*)d_in[13];
  const float* fc2_b  = (const float*)d_in[14];
  const float* g1     = (const float*)d_in[15];
  const float* g2     = (const float*)d_in[16];

  char* ws = (char*)d_ws;
  uint16_t* qkvw_bf  = (uint16_t*)(ws + 0);
  uint16_t* projw_bf = (uint16_t*)(ws + 3538944);
  uint16_t* fc1w_bf  = (uint16_t*)(ws + 4718592);
  uint16_t* fc2w_bf  = (uint16_t*)(ws + 9437184);
  float*    qkvbias  = (float*)(ws + 14155776);
  uint16_t* h_bf     = (uint16_t*)(ws + 14164992);
  uint16_t* qkv_bf   = (uint16_t*)(ws + 20456448);
  uint16_t* vt_bf    = (uint16_t*)(ws + 39330816);
  uint16_t* o_bf     = (uint16_t*)(ws + 45622272);
  float*    x1_f     = (float*)(ws + 51913728);
  uint16_t* fc1_bf   = qkv_bf;
  uint16_t* h2_bf    = h_bf;

  const int M = BATCH * NSEQ;

  cvt4_kernel<<<(N_QKVW + N_PROJW + N_FC1W + N_FC2W) / 1024, 256, 0, stream>>>(
      qkv_w, proj_w, fc1_w, fc2_w, qkvw_bf, projw_bf, fc1w_bf, fc2w_bf);
  bias_kernel<<<(3 * DMODEL + 255) / 256, 256, 0, stream>>>(q_bias, v_bias, qkvbias);

  ln_kernel<<<M, 256, 0, stream>>>(x, ln1_g, ln1_b, h_bf);
  gemm128<0><<<dim3((3 * DMODEL) / 128, M / 128), 256, 0, stream>>>(
      h_bf, qkvw_bf, qkvbias, qkv_bf, M, 3 * DMODEL, DMODEL);
  vtrans_kernel<<<dim3(BATCH * NHEAD, NSEQ / 64), 256, 0, stream>>>(qkv_bf, vt_bf);
  attn_kernel<<<dim3(BATCH * NHEAD, NSEQ / 64), 128, 0, stream>>>(qkv_bf, vt_bf, amask, o_bf);
  gemm64<<<dim3(DMODEL / 64, M / 128), 256, 0, stream>>>(
      o_bf, projw_bf, proj_b, x1_f, x, g1, M, DMODEL, DMODEL);
  ln_kernel<<<M, 256, 0, stream>>>(x1_f, ln2_g, ln2_b, h2_bf);
  gemm128<2><<<dim3(HIDDEN / 128, M / 128), 256, 0, stream>>>(
      h2_bf, fc1w_bf, fc1_b, fc1_bf, M, HIDDEN, DMODEL);
  gemm64<<<dim3(DMODEL / 64, M / 128), 256, 0, stream>>>(
      fc1_bf, fc2w_bf, fc2_b, (float*)d_out, x1_f, g2, M, DMODEL, HIDDEN);
}

// Round 7
// 222.216 us; speedup vs baseline: 1.1596x; 1.1596x over previous
//
#include <hip/hip_runtime.h>
#include <hip/hip_bf16.h>
#include <stdint.h>

// ---------------- types / helpers ----------------
typedef __bf16 bf16x8 __attribute__((ext_vector_type(8)));
typedef unsigned short u16x8 __attribute__((ext_vector_type(8)));
typedef float f32x4 __attribute__((ext_vector_type(4)));
typedef float f32x16 __attribute__((ext_vector_type(16)));
typedef uint32_t u32x4 __attribute__((ext_vector_type(4)));

#define DMODEL 768
#define NSEQ   2048
#define BATCH  2
#define NHEAD  12
#define HDIM   64
#define HIDDEN 3072
#define PROWS  (BATCH * NHEAD * NSEQ)   // 49152 attention rows
// 0.125 * log2(e): fold softmax scale AND exp->exp2 conversion into Q
#define QSCALE 0.18033688011112042f

__device__ __forceinline__ uint16_t f2bf(float f) {
  __hip_bfloat16 h = __float2bfloat16(f);
  return __builtin_bit_cast(uint16_t, h);
}
__device__ __forceinline__ float bf2f(uint16_t u) {
  uint32_t x = (uint32_t)u << 16;
  return __builtin_bit_cast(float, x);
}
__device__ __forceinline__ bf16x8 ldb8(const uint16_t* p) {
  return __builtin_bit_cast(bf16x8, *reinterpret_cast<const u16x8*>(p));
}

using as1_void = __attribute__((address_space(1))) const void;
using as3_void = __attribute__((address_space(3))) void;
__device__ __forceinline__ void gload16(const uint16_t* src, uint16_t* lds) {
  __builtin_amdgcn_global_load_lds((as1_void*)src, (as3_void*)lds, 16, 0, 0);
}
#define MEMFENCE asm volatile("" ::: "memory")

// ---------------- fused fp32 -> bf16 casts ----------------
#define N_QKVW  (3 * DMODEL * DMODEL)
#define N_PROJW (DMODEL * DMODEL)
#define N_FC1W  (HIDDEN * DMODEL)
#define N_FC2W  (DMODEL * HIDDEN)
__global__ __launch_bounds__(256) void cvt4_kernel(const float* __restrict__ s0,
                                                   const float* __restrict__ s1,
                                                   const float* __restrict__ s2,
                                                   const float* __restrict__ s3,
                                                   uint16_t* __restrict__ d0,
                                                   uint16_t* __restrict__ d1,
                                                   uint16_t* __restrict__ d2,
                                                   uint16_t* __restrict__ d3) {
  int i4 = (blockIdx.x * 256 + threadIdx.x) * 4;
  const float* s;
  uint16_t* d;
  if (i4 < N_QKVW) { s = s0 + i4; d = d0 + i4; }
  else if (i4 < N_QKVW + N_PROJW) { int j = i4 - N_QKVW; s = s1 + j; d = d1 + j; }
  else if (i4 < N_QKVW + N_PROJW + N_FC1W) { int j = i4 - N_QKVW - N_PROJW; s = s2 + j; d = d2 + j; }
  else { int j = i4 - N_QKVW - N_PROJW - N_FC1W; s = s3 + j; d = d3 + j; }
  float4 v = *reinterpret_cast<const float4*>(s);
  ushort4 o;
  o.x = f2bf(v.x); o.y = f2bf(v.y); o.z = f2bf(v.z); o.w = f2bf(v.w);
  *reinterpret_cast<ushort4*>(d) = o;
}

// ---------------- qkv bias assembly ----------------
__global__ __launch_bounds__(256) void bias_kernel(const float* __restrict__ qb,
                                                   const float* __restrict__ vb,
                                                   float* __restrict__ out) {
  int j = blockIdx.x * 256 + threadIdx.x;
  if (j < 3 * DMODEL) {
    float v = 0.f;
    if (j < DMODEL) v = qb[j];
    else if (j >= 2 * DMODEL) v = vb[j - 2 * DMODEL];
    out[j] = v;
  }
}

// ---------------- layernorm: fp32 in -> bf16 out ----------------
__global__ __launch_bounds__(256) void ln_kernel(const float* __restrict__ x,
                                                 const float* __restrict__ g,
                                                 const float* __restrict__ bt,
                                                 uint16_t* __restrict__ out) {
  const int row = blockIdx.x;
  const int t = threadIdx.x;
  const float* xr = x + (size_t)row * DMODEL;
  float v0 = xr[t], v1 = xr[t + 256], v2 = xr[t + 512];
  float s = v0 + v1 + v2;
  float q = v0 * v0 + v1 * v1 + v2 * v2;
  for (int off = 32; off >= 1; off >>= 1) {
    s += __shfl_xor(s, off);
    q += __shfl_xor(q, off);
  }
  __shared__ float ss[4], sq[4];
  int w = t >> 6;
  if ((t & 63) == 0) { ss[w] = s; sq[w] = q; }
  __syncthreads();
  s = ss[0] + ss[1] + ss[2] + ss[3];
  q = sq[0] + sq[1] + sq[2] + sq[3];
  const float mean = s * (1.0f / DMODEL);
  const float var = q * (1.0f / DMODEL) - mean * mean;
  const float rstd = rsqrtf(var + 1e-5f);
  uint16_t* orow = out + (size_t)row * DMODEL;
  orow[t]       = f2bf((v0 - mean) * rstd * g[t]       + bt[t]);
  orow[t + 256] = f2bf((v1 - mean) * rstd * g[t + 256] + bt[t + 256]);
  orow[t + 512] = f2bf((v2 - mean) * rstd * g[t + 512] + bt[t + 512]);
}

// ------------- GEMM A: 128x128 block, 4 waves x (64x64), dbuf counted-vmcnt ----
template <int MODE>
__global__ __launch_bounds__(256, 3) void gemm128(const uint16_t* __restrict__ A,
                                                  const uint16_t* __restrict__ W,
                                                  const float* __restrict__ bias,
                                                  void* __restrict__ outp,
                                                  int M, int N, int K) {
  __shared__ uint16_t As[2][128 * 32];
  __shared__ uint16_t Bs[2][128 * 32];
  const int tid = threadIdx.x;
  const int lane = tid & 63;
  const int w = tid >> 6;
  const int wr = w >> 1, wc = w & 1;
  const int row0 = blockIdx.y * 128;
  const int col0 = blockIdx.x * 128;
  const int lr = lane & 15;
  const int g = lane >> 4;

  const int o0 = w * 1024 + lane * 16;
  const int o1 = o0 + 4096;
  const int r0s = o0 >> 6, c0s = (o0 & 63) >> 1;
  const int r1s = o1 >> 6, c1s = (o1 & 63) >> 1;
  const int l0 = (w * 1024) >> 1;
  const int l1 = l0 + 2048;
  const uint16_t* Abase = A + (size_t)row0 * K;
  const uint16_t* Wbase = W + (size_t)col0 * K;

  auto stage = [&](int kt) {
    uint16_t* Ad = &As[kt & 1][0];
    uint16_t* Bd = &Bs[kt & 1][0];
    const int kk = kt * 32;
    gload16(Abase + (size_t)r0s * K + kk + c0s, Ad + l0);
    gload16(Abase + (size_t)r1s * K + kk + c1s, Ad + l1);
    gload16(Wbase + (size_t)r0s * K + kk + c0s, Bd + l0);
    gload16(Wbase + (size_t)r1s * K + kk + c1s, Bd + l1);
  };

  f32x4 acc[4][4] = {};
  const int nt = K >> 5;
  stage(0);
  for (int kt = 0; kt < nt; ++kt) {
    if (kt + 1 < nt) {
      stage(kt + 1);
      asm volatile("s_waitcnt vmcnt(4)" ::: "memory");
    } else {
      asm volatile("s_waitcnt vmcnt(0)" ::: "memory");
    }
    __builtin_amdgcn_s_barrier();
    MEMFENCE;
    const uint16_t* Ab = &As[kt & 1][0];
    const uint16_t* Bb = &Bs[kt & 1][0];
    bf16x8 a[4], b[4];
#pragma unroll
    for (int m = 0; m < 4; ++m) a[m] = ldb8(Ab + (wr * 64 + m * 16 + lr) * 32 + g * 8);
#pragma unroll
    for (int n = 0; n < 4; ++n) b[n] = ldb8(Bb + (wc * 64 + n * 16 + lr) * 32 + g * 8);
#pragma unroll
    for (int m = 0; m < 4; ++m)
#pragma unroll
      for (int n = 0; n < 4; ++n)
        acc[m][n] = __builtin_amdgcn_mfma_f32_16x16x32_bf16(a[m], b[n], acc[m][n], 0, 0, 0);
    MEMFENCE;
    __builtin_amdgcn_s_barrier();
  }

#pragma unroll
  for (int m = 0; m < 4; ++m) {
    int row = row0 + wr * 64 + m * 16 + g * 4;
#pragma unroll
    for (int n = 0; n < 4; ++n) {
      int col = col0 + wc * 64 + n * 16 + lr;
      float bv = bias[col];
#pragma unroll
      for (int ri = 0; ri < 4; ++ri) {
        float val = acc[m][n][ri] + bv;
        size_t idx = (size_t)(row + ri) * N + col;
        if constexpr (MODE == 0) {
          if (col < DMODEL) val *= QSCALE;   // fold attn scale + log2e into Q
          ((uint16_t*)outp)[idx] = f2bf(val);
        } else {
          float ge = 0.5f * val * (1.0f + erff(val * 0.70710678118654752f));
          ((uint16_t*)outp)[idx] = f2bf(ge);
        }
      }
    }
  }
}

// ------------- GEMM B: 64x64 block, 2 waves (N=768 shapes -> 768 blocks = 3/CU)
__global__ __launch_bounds__(128, 2) void gemm64(const uint16_t* __restrict__ A,
                                                 const uint16_t* __restrict__ W,
                                                 const float* __restrict__ bias,
                                                 float* __restrict__ outp,
                                                 const float* __restrict__ resid,
                                                 const float* __restrict__ gamma,
                                                 int M, int N, int K) {
  __shared__ uint16_t As[2][64 * 32];
  __shared__ uint16_t Bs[2][64 * 32];
  const int tid = threadIdx.x;
  const int lane = tid & 63;
  const int wv = tid >> 6;
  const int row0 = blockIdx.y * 64;
  const int col0 = blockIdx.x * 64;
  const int lr = lane & 15;
  const int g = lane >> 4;
  const int rs = tid >> 2;            // 0..31 (+32 for issue 1)
  const int cs = (tid & 3) * 8;
  const uint16_t* Abase = A + (size_t)row0 * K;
  const uint16_t* Wbase = W + (size_t)col0 * K;

  auto stage = [&](int kt) {
    uint16_t* Ad = &As[kt & 1][0];
    uint16_t* Bd = &Bs[kt & 1][0];
    const int kk = kt * 32;
#pragma unroll
    for (int i = 0; i < 2; ++i) {
      gload16(Abase + (size_t)(i * 32 + rs) * K + kk + cs, Ad + i * 1024 + wv * 512);
      gload16(Wbase + (size_t)(i * 32 + rs) * K + kk + cs, Bd + i * 1024 + wv * 512);
    }
  };

  f32x4 acc[4][2] = {};
  const int nt = K >> 5;
  stage(0);
  for (int kt = 0; kt < nt; ++kt) {
    if (kt + 1 < nt) {
      stage(kt + 1);
      asm volatile("s_waitcnt vmcnt(4)" ::: "memory");
    } else {
      asm volatile("s_waitcnt vmcnt(0)" ::: "memory");
    }
    __builtin_amdgcn_s_barrier();
    MEMFENCE;
    const uint16_t* Ab = &As[kt & 1][0];
    const uint16_t* Bb = &Bs[kt & 1][0];
    bf16x8 a[4], b[2];
#pragma unroll
    for (int m = 0; m < 4; ++m) a[m] = ldb8(Ab + (m * 16 + lr) * 32 + g * 8);
#pragma unroll
    for (int n = 0; n < 2; ++n) b[n] = ldb8(Bb + (wv * 32 + n * 16 + lr) * 32 + g * 8);
#pragma unroll
    for (int m = 0; m < 4; ++m)
#pragma unroll
      for (int n = 0; n < 2; ++n)
        acc[m][n] = __builtin_amdgcn_mfma_f32_16x16x32_bf16(a[m], b[n], acc[m][n], 0, 0, 0);
    MEMFENCE;
    __builtin_amdgcn_s_barrier();
  }

#pragma unroll
  for (int m = 0; m < 4; ++m) {
    int row = row0 + m * 16 + g * 4;
#pragma unroll
    for (int n = 0; n < 2; ++n) {
      int col = col0 + wv * 32 + n * 16 + lr;
      float bv = bias[col];
      float gv = gamma[col];
#pragma unroll
      for (int ri = 0; ri < 4; ++ri) {
        float val = acc[m][n][ri] + bv;
        size_t idx = (size_t)(row + ri) * N + col;
        outp[idx] = resid[idx] + gv * val;
      }
    }
  }
}

// ---------------- prep: masked-K copy + masked-V transpose ---------------------
// km[b*N+n][768]: K with masked rows zeroed. vt[bh][d][n]: V^T, masked cols zeroed.
__global__ __launch_bounds__(256) void prep_kernel(const uint16_t* __restrict__ qkv,
                                                   const int* __restrict__ mask,
                                                   uint16_t* __restrict__ km,
                                                   uint16_t* __restrict__ vt) {
  __shared__ uint16_t tile[64][72];
  const int t = threadIdx.x;
  const int bh = blockIdx.x;
  const int n0 = blockIdx.y * 64;
  const int b = bh / NHEAD, h = bh % NHEAD;
  const int* mb = mask + b * NSEQ;
  const uint16_t* src = qkv + (size_t)(b * NSEQ + n0) * (3 * DMODEL) + h * HDIM;
  uint16_t* kdst = km + (size_t)(b * NSEQ + n0) * DMODEL + h * HDIM;
#pragma unroll
  for (int it = 0; it < 2; ++it) {
    int slot = it * 256 + t;
    int r = slot >> 2, c = (slot & 3) * 16;
    uint16_t mz = (mb[n0 + r] != 0) ? (uint16_t)0xFFFF : (uint16_t)0;
    const uint16_t* rp = src + (size_t)r * (3 * DMODEL);
    u16x8 k0 = *reinterpret_cast<const u16x8*>(rp + DMODEL + c) & mz;
    u16x8 k1 = *reinterpret_cast<const u16x8*>(rp + DMODEL + c + 8) & mz;
    u16x8 v0 = *reinterpret_cast<const u16x8*>(rp + 2 * DMODEL + c) & mz;
    u16x8 v1 = *reinterpret_cast<const u16x8*>(rp + 2 * DMODEL + c + 8) & mz;
    *reinterpret_cast<u16x8*>(kdst + (size_t)r * DMODEL + c) = k0;
    *reinterpret_cast<u16x8*>(kdst + (size_t)r * DMODEL + c + 8) = k1;
    *reinterpret_cast<u16x8*>(&tile[r][c]) = v0;
    *reinterpret_cast<u16x8*>(&tile[r][c + 8]) = v1;
  }
  __syncthreads();
  uint16_t* dst = vt + (size_t)bh * HDIM * NSEQ + n0;
#pragma unroll
  for (int it = 0; it < 2; ++it) {
    int slot = it * 256 + t;
    int d = slot >> 2, c = (slot & 3) * 16;
    u16x8 a0, a1;
#pragma unroll
    for (int e = 0; e < 8; ++e) a0[e] = tile[c + e][d];
#pragma unroll
    for (int e = 0; e < 8; ++e) a1[e] = tile[c + 8 + e][d];
    *reinterpret_cast<u16x8*>(dst + (size_t)d * NSEQ + c) = a0;
    *reinterpret_cast<u16x8*>(dst + (size_t)d * NSEQ + c + 8) = a1;
  }
}

// ---------------- flash attention v5: split-KV, maskless exp2 hot loop ---------
// grid (24, 16, 2): 4 waves x 32 q-rows, half z covers keys [z*1024, +1024).
// Masked K rows / V cols pre-zeroed -> masked scores exactly 0; inflated max
// (init 0) keeps softmax invariant; per-tile wave-uniform correction removes
// the cnt*exp2(-m) junk from lsum. Unnormalized bf16 partials + (m,lsum) out.
__global__ __launch_bounds__(256, 3) void attn_kernel(const uint16_t* __restrict__ qkv,
                                                      const uint16_t* __restrict__ km,
                                                      const uint16_t* __restrict__ vt,
                                                      const int* __restrict__ mask,
                                                      uint16_t* __restrict__ po,
                                                      float* __restrict__ pml) {
  __shared__ uint16_t Kb[2][64 * 64];
  __shared__ uint16_t Vb[2][64 * 64];
  __shared__ unsigned long long mbits[16];
  const int tid = threadIdx.x;
  const int lane = tid & 63;
  const int w = tid >> 6;            // 4 waves
  const int bh = blockIdx.x;
  const int b = bh / NHEAD, hd = bh % NHEAD;
  const int z = blockIdx.z;
  const int kbase = z * 1024;
  const int q0 = blockIdx.y * 128 + w * 32;
  const int l31 = lane & 31;
  const int hh = lane >> 5;

  // mask bits for this half's 16 tiles (popcount correction only)
  const int* mb = mask + b * NSEQ;
#pragma unroll
  for (int it = 0; it < 4; ++it) {
    unsigned long long bm = __ballot(mb[kbase + it * 256 + tid] != 0);
    if (lane == 0) mbits[it * 4 + w] = bm;
  }

  bf16x8 qa[4];
  const uint16_t* qptr = qkv + (size_t)(b * NSEQ + q0 + l31) * (3 * DMODEL) + hd * HDIM + hh * 8;
#pragma unroll
  for (int dblk = 0; dblk < 4; ++dblk) qa[dblk] = ldb8(qptr + dblk * 16);

  const uint16_t* kmb = km + (size_t)b * NSEQ * DMODEL + hd * HDIM;
  const uint16_t* vtb = vt + (size_t)bh * HDIM * NSEQ;

  __syncthreads();   // mbits visible

  const int srow = tid >> 3;                      // 0..31
  const int sxor = ((tid & 7) ^ (srow & 7)) * 8;  // pre-swizzled source chunk
  auto stage = [&](int t) {
    const int pb = t & 1;
    const int k0 = kbase + t * 64;
#pragma unroll
    for (int i = 0; i < 2; ++i) {
      const int row = i * 32 + srow;
      gload16(kmb + (size_t)(k0 + row) * DMODEL + sxor, &Kb[pb][i * 2048 + w * 512]);
      gload16(vtb + (size_t)row * NSEQ + k0 + sxor, &Vb[pb][i * 2048 + w * 512]);
    }
  };

  float m_ = 0.f, lsum = 0.f;        // inflated-max start (valid: masked s == 0)
  f32x16 oacc[2] = {};

  stage(0);
  for (int t = 0; t < 16; ++t) {
    if (t + 1 < 16) {
      stage(t + 1);
      asm volatile("s_waitcnt vmcnt(4)" ::: "memory");
    } else {
      asm volatile("s_waitcnt vmcnt(0)" ::: "memory");
    }
    __builtin_amdgcn_s_barrier();
    MEMFENCE;
    const uint16_t* Kbp = &Kb[t & 1][0];
    const uint16_t* Vbp = &Vb[t & 1][0];

    // S^T[k][q] = mfma(K, Q); lane = q, regs = k
    f32x16 st[2];
    __builtin_amdgcn_s_setprio(1);
#pragma unroll
    for (int kblk = 0; kblk < 2; ++kblk) {
      f32x16 acc = {};
      const uint16_t* kr = Kbp + (kblk * 32 + l31) * 64;
#pragma unroll
      for (int dblk = 0; dblk < 4; ++dblk) {
        bf16x8 kf = ldb8(kr + ((dblk * 2 + hh) ^ (l31 & 7)) * 8);
        acc = __builtin_amdgcn_mfma_f32_32x32x16_bf16(kf, qa[dblk], acc, 0, 0, 0);
      }
      st[kblk] = acc;
    }
    __builtin_amdgcn_s_setprio(0);

    // row max (no mask handling: masked scores are exactly 0, m_ >= 0 inflated)
    float tm = -1e30f;
#pragma unroll
    for (int kblk = 0; kblk < 2; ++kblk)
#pragma unroll
      for (int r = 0; r < 16; ++r) tm = fmaxf(tm, st[kblk][r]);
    tm = fmaxf(tm, __shfl_xor(tm, 32));
    if (__any(tm - m_ > 16.0f)) {      // defer-max, log2 units
      float mn = fmaxf(m_, tm);
      float al = exp2f(m_ - mn);
      lsum *= al;
      m_ = mn;
      float ar[16];
#pragma unroll
      for (int r = 0; r < 16; ++r)
        ar[r] = __shfl(al, (r & 3) + 8 * (r >> 2) + 4 * hh);
#pragma unroll
      for (int dblk = 0; dblk < 2; ++dblk)
#pragma unroll
        for (int r = 0; r < 16; ++r) oacc[dblk][r] *= ar[r];
    }

    // exp2 + pack + sum (4 VALU ops/element, no mask)
    float ls = 0.f;
    uint32_t pk[2][8];
#pragma unroll
    for (int kblk = 0; kblk < 2; ++kblk)
#pragma unroll
      for (int wn = 0; wn < 8; ++wn) {
        float e0 = exp2f(st[kblk][2 * wn] - m_);
        float e1 = exp2f(st[kblk][2 * wn + 1] - m_);
        ls += e0 + e1;
        pk[kblk][wn] = (uint32_t)f2bf(e0) | ((uint32_t)f2bf(e1) << 16);
      }
    ls += __shfl_xor(ls, 32);
    // remove masked-key junk: each masked k contributed exactly exp2(0 - m_)
    const unsigned long long wb = mbits[t];
    const float cnt = (float)(64 - __popcll(wb));
    ls -= cnt * exp2f(0.f - m_);
    lsum += ls;

    // gather PV A-frags (same algebra as v4)
    bf16x8 af[4];
#pragma unroll
    for (int kb16 = 0; kb16 < 4; ++kb16) {
      const int kblk = kb16 >> 1;
      const int a4 = (kb16 & 1) * 4;
      uint32_t ow0 = hh ? pk[kblk][a4 + 2] : pk[kblk][a4 + 0];
      uint32_t ow1 = hh ? pk[kblk][a4 + 3] : pk[kblk][a4 + 1];
      uint32_t gv0 = hh ? pk[kblk][a4 + 0] : pk[kblk][a4 + 2];
      uint32_t gv1 = hh ? pk[kblk][a4 + 1] : pk[kblk][a4 + 3];
      uint32_t sw0 = (uint32_t)__shfl_xor((int)gv0, 32);
      uint32_t sw1 = (uint32_t)__shfl_xor((int)gv1, 32);
      u32x4 afu;
      afu[0] = hh ? sw0 : ow0;
      afu[1] = hh ? sw1 : ow1;
      afu[2] = hh ? ow0 : sw0;
      afu[3] = hh ? ow1 : sw1;
      af[kb16] = __builtin_bit_cast(bf16x8, afu);
    }

    __builtin_amdgcn_s_setprio(1);
#pragma unroll
    for (int dblk = 0; dblk < 2; ++dblk) {
      const uint16_t* vr = Vbp + (dblk * 32 + l31) * 64;
#pragma unroll
      for (int kb16 = 0; kb16 < 4; ++kb16) {
        bf16x8 vf = ldb8(vr + ((kb16 * 2 + hh) ^ (l31 & 7)) * 8);
        oacc[dblk] = __builtin_amdgcn_mfma_f32_32x32x16_bf16(af[kb16], vf, oacc[dblk], 0, 0, 0);
      }
    }
    __builtin_amdgcn_s_setprio(0);
    MEMFENCE;
    __builtin_amdgcn_s_barrier();
  }

  // write unnormalized partial O (bf16) + (m, lsum)
  uint16_t* ob = po + ((size_t)z * PROWS + (size_t)bh * NSEQ + q0) * 64;
#pragma unroll
  for (int r = 0; r < 16; ++r) {
    const int qrow = (r & 3) + 8 * (r >> 2) + 4 * hh;
#pragma unroll
    for (int dblk = 0; dblk < 2; ++dblk)
      ob[(size_t)qrow * 64 + dblk * 32 + l31] = f2bf(oacc[dblk][r]);
  }
  if (hh == 0) {
    float2* pp = (float2*)(pml + ((size_t)z * PROWS + (size_t)bh * NSEQ + q0 + l31) * 2);
    *pp = make_float2(m_, lsum);
  }
}

// ---------------- merge split-KV partials -> o_bf ------------------------------
__global__ __launch_bounds__(256) void merge_kernel(const uint16_t* __restrict__ po,
                                                    const float* __restrict__ pml,
                                                    uint16_t* __restrict__ o) {
  int gid = blockIdx.x * 256 + threadIdx.x;   // 393216 = 49152 rows x 8 chunks
  int row = gid >> 3;
  int c0 = (gid & 7) * 8;
  float m1 = pml[(size_t)row * 2], l1 = pml[(size_t)row * 2 + 1];
  float m2 = pml[((size_t)PROWS + row) * 2], l2 = pml[((size_t)PROWS + row) * 2 + 1];
  float M = fmaxf(m1, m2);
  float w1 = exp2f(m1 - M), w2 = exp2f(m2 - M);
  float L = w1 * l1 + w2 * l2;
  float inv = L > 0.f ? 1.f / L : 0.f;
  w1 *= inv; w2 *= inv;
  u16x8 a = *reinterpret_cast<const u16x8*>(po + (size_t)row * 64 + c0);
  u16x8 b = *reinterpret_cast<const u16x8*>(po + ((size_t)PROWS + row) * 64 + c0);
  int bh = row >> 11, q = row & 2047;
  int bb = bh / NHEAD, hh = bh % NHEAD;
  uint16_t* op = o + ((size_t)(bb * NSEQ + q) * DMODEL + hh * HDIM + c0);
  u16x8 outv;
#pragma unroll
  for (int e = 0; e < 8; ++e)
    outv[e] = f2bf(w1 * bf2f(a[e]) + w2 * bf2f(b[e]));
  *reinterpret_cast<u16x8*>(op) = outv;
}

// ---------------- host ----------------
extern "C" void kernel_launch(void* const* d_in, const int* in_sizes, int n_in,
                              void* d_out, int out_size, void* d_ws, size_t ws_size,
                              hipStream_t stream) {
  const float* x      = (const float*)d_in[0];
  const int*   amask  = (const int*)d_in[1];
  const float* ln1_g  = (const float*)d_in[2];
  const float* ln1_b  = (const float*)d_in[3];
  const float* qkv_w  = (const float*)d_in[4];
  const float* q_bias = (const float*)d_in[5];
  const float* v_bias = (const float*)d_in[6];
  const float* proj_w = (const float*)d_in[7];
  const float* proj_b = (const float*)d_in[8];
  const float* ln2_g  = (const float*)d_in[9];
  const float* ln2_b  = (const float*)d_in[10];
  const float* fc1_w  = (const float*)d_in[11];
  const float* fc1_b  = (const float*)d_in[12];
  const float* fc2_w  = (const float*)d_in[13];
  const float* fc2_b  = (const float*)d_in[14];
  const float* g1     = (const float*)d_in[15];
  const float* g2     = (const float*)d_in[16];

  char* ws = (char*)d_ws;
  uint16_t* qkvw_bf  = (uint16_t*)(ws + 0);          // 3.5 MB
  uint16_t* projw_bf = (uint16_t*)(ws + 3538944);
  uint16_t* fc1w_bf  = (uint16_t*)(ws + 4718592);
  uint16_t* fc2w_bf  = (uint16_t*)(ws + 9437184);
  float*    qkvbias  = (float*)(ws + 14155776);
  uint16_t* h_bf     = (uint16_t*)(ws + 14164992);   // ln1 out; dead after qkv gemm
  uint16_t* km       = h_bf;                         // masked-K alias (6.29 MB, exact)
  uint16_t* h2_bf    = h_bf;                         // ln2 out (after attn)
  uint16_t* qkv_bf   = (uint16_t*)(ws + 20456448);   // 18.9 MB (fc1 out reuses + vt)
  uint16_t* vt_bf    = (uint16_t*)(ws + 39330816);   // 6.29 MB
  uint16_t* o_bf     = (uint16_t*)(ws + 45622272);   // 6.29 MB
  float*    x1_f     = (float*)(ws + 51913728);      // 12.58 MB (proj out)
  uint16_t* po       = (uint16_t*)(ws + 51913728);   // partials alias x1_f (dead then)
  float*    pml      = (float*)(ws + 64496640);      // 0.79 MB (m,lsum pairs)
  uint16_t* fc1_bf   = qkv_bf;

  const int M = BATCH * NSEQ;

  cvt4_kernel<<<(N_QKVW + N_PROJW + N_FC1W + N_FC2W) / 1024, 256, 0, stream>>>(
      qkv_w, proj_w, fc1_w, fc2_w, qkvw_bf, projw_bf, fc1w_bf, fc2w_bf);
  bias_kernel<<<(3 * DMODEL + 255) / 256, 256, 0, stream>>>(q_bias, v_bias, qkvbias);

  ln_kernel<<<M, 256, 0, stream>>>(x, ln1_g, ln1_b, h_bf);
  gemm128<0><<<dim3((3 * DMODEL) / 128, M / 128), 256, 0, stream>>>(
      h_bf, qkvw_bf, qkvbias, qkv_bf, M, 3 * DMODEL, DMODEL);
  prep_kernel<<<dim3(BATCH * NHEAD, NSEQ / 64), 256, 0, stream>>>(qkv_bf, amask, km, vt_bf);
  attn_kernel<<<dim3(BATCH * NHEAD, NSEQ / 128, 2), 256, 0, stream>>>(
      qkv_bf, km, vt_bf, amask, po, pml);
  merge_kernel<<<(PROWS * 8) / 256, 256, 0, stream>>>(po, pml, o_bf);
  gemm64<<<dim3(DMODEL / 64, M / 64), 128, 0, stream>>>(
      o_bf, projw_bf, proj_b, x1_f, x, g1, M, DMODEL, DMODEL);
  ln_kernel<<<M, 256, 0, stream>>>(x1_f, ln2_g, ln2_b, h2_bf);
  gemm128<2><<<dim3(HIDDEN / 128, M / 128), 256, 0, stream>>>(
      h2_bf, fc1w_bf, fc1_b, fc1_bf, M, HIDDEN, DMODEL);
  gemm64<<<dim3(DMODEL / 64, M / 64), 128, 0, stream>>>(
      fc1_bf, fc2w_bf, fc2_b, (float*)d_out, x1_f, g2, M, DMODEL, HIDDEN);
}

// Round 8
// 202.708 us; speedup vs baseline: 1.2712x; 1.0962x over previous
//
#include <hip/hip_runtime.h>
#include <hip/hip_bf16.h>
#include <stdint.h>

// ---------------- types / helpers ----------------
typedef __bf16 bf16x8 __attribute__((ext_vector_type(8)));
typedef unsigned short u16x8 __attribute__((ext_vector_type(8)));
typedef float f32x4 __attribute__((ext_vector_type(4)));
typedef float f32x16 __attribute__((ext_vector_type(16)));
typedef uint32_t u32x4 __attribute__((ext_vector_type(4)));

#define DMODEL 768
#define NSEQ   2048
#define BATCH  2
#define NHEAD  12
#define HDIM   64
#define HIDDEN 3072
#define PROWS  (BATCH * NHEAD * NSEQ)   // 49152 attention rows
// 0.125 * log2(e): fold softmax scale AND exp->exp2 conversion into Q
#define QSCALE 0.18033688011112042f

__device__ __forceinline__ uint16_t f2bf(float f) {
  __hip_bfloat16 h = __float2bfloat16(f);
  return __builtin_bit_cast(uint16_t, h);
}
__device__ __forceinline__ float bf2f(uint16_t u) {
  uint32_t x = (uint32_t)u << 16;
  return __builtin_bit_cast(float, x);
}
__device__ __forceinline__ bf16x8 ldb8(const uint16_t* p) {
  return __builtin_bit_cast(bf16x8, *reinterpret_cast<const u16x8*>(p));
}

using as1_void = __attribute__((address_space(1))) const void;
using as3_void = __attribute__((address_space(3))) void;
__device__ __forceinline__ void gload16(const uint16_t* src, uint16_t* lds) {
  __builtin_amdgcn_global_load_lds((as1_void*)src, (as3_void*)lds, 16, 0, 0);
}
#define MEMFENCE asm volatile("" ::: "memory")

// ---------------- fused fp32 -> bf16 casts ----------------
#define N_QKVW  (3 * DMODEL * DMODEL)
#define N_PROJW (DMODEL * DMODEL)
#define N_FC1W  (HIDDEN * DMODEL)
#define N_FC2W  (DMODEL * HIDDEN)
__global__ __launch_bounds__(256) void cvt4_kernel(const float* __restrict__ s0,
                                                   const float* __restrict__ s1,
                                                   const float* __restrict__ s2,
                                                   const float* __restrict__ s3,
                                                   uint16_t* __restrict__ d0,
                                                   uint16_t* __restrict__ d1,
                                                   uint16_t* __restrict__ d2,
                                                   uint16_t* __restrict__ d3) {
  int i4 = (blockIdx.x * 256 + threadIdx.x) * 4;
  const float* s;
  uint16_t* d;
  if (i4 < N_QKVW) { s = s0 + i4; d = d0 + i4; }
  else if (i4 < N_QKVW + N_PROJW) { int j = i4 - N_QKVW; s = s1 + j; d = d1 + j; }
  else if (i4 < N_QKVW + N_PROJW + N_FC1W) { int j = i4 - N_QKVW - N_PROJW; s = s2 + j; d = d2 + j; }
  else { int j = i4 - N_QKVW - N_PROJW - N_FC1W; s = s3 + j; d = d3 + j; }
  float4 v = *reinterpret_cast<const float4*>(s);
  ushort4 o;
  o.x = f2bf(v.x); o.y = f2bf(v.y); o.z = f2bf(v.z); o.w = f2bf(v.w);
  *reinterpret_cast<ushort4*>(d) = o;
}

// ---------------- qkv bias assembly ----------------
__global__ __launch_bounds__(256) void bias_kernel(const float* __restrict__ qb,
                                                   const float* __restrict__ vb,
                                                   float* __restrict__ out) {
  int j = blockIdx.x * 256 + threadIdx.x;
  if (j < 3 * DMODEL) {
    float v = 0.f;
    if (j < DMODEL) v = qb[j];
    else if (j >= 2 * DMODEL) v = vb[j - 2 * DMODEL];
    out[j] = v;
  }
}

// ---------------- layernorm: fp32 in -> bf16 out ----------------
__global__ __launch_bounds__(256) void ln_kernel(const float* __restrict__ x,
                                                 const float* __restrict__ g,
                                                 const float* __restrict__ bt,
                                                 uint16_t* __restrict__ out) {
  const int row = blockIdx.x;
  const int t = threadIdx.x;
  const float* xr = x + (size_t)row * DMODEL;
  float v0 = xr[t], v1 = xr[t + 256], v2 = xr[t + 512];
  float s = v0 + v1 + v2;
  float q = v0 * v0 + v1 * v1 + v2 * v2;
  for (int off = 32; off >= 1; off >>= 1) {
    s += __shfl_xor(s, off);
    q += __shfl_xor(q, off);
  }
  __shared__ float ss[4], sq[4];
  int w = t >> 6;
  if ((t & 63) == 0) { ss[w] = s; sq[w] = q; }
  __syncthreads();
  s = ss[0] + ss[1] + ss[2] + ss[3];
  q = sq[0] + sq[1] + sq[2] + sq[3];
  const float mean = s * (1.0f / DMODEL);
  const float var = q * (1.0f / DMODEL) - mean * mean;
  const float rstd = rsqrtf(var + 1e-5f);
  uint16_t* orow = out + (size_t)row * DMODEL;
  orow[t]       = f2bf((v0 - mean) * rstd * g[t]       + bt[t]);
  orow[t + 256] = f2bf((v1 - mean) * rstd * g[t + 256] + bt[t + 256]);
  orow[t + 512] = f2bf((v2 - mean) * rstd * g[t + 512] + bt[t + 512]);
}

// ------------- GEMM A: 128x128 block, 4 waves x (64x64), dbuf counted-vmcnt ----
template <int MODE>
__global__ __launch_bounds__(256, 3) void gemm128(const uint16_t* __restrict__ A,
                                                  const uint16_t* __restrict__ W,
                                                  const float* __restrict__ bias,
                                                  void* __restrict__ outp,
                                                  int M, int N, int K) {
  __shared__ uint16_t As[2][128 * 32];
  __shared__ uint16_t Bs[2][128 * 32];
  const int tid = threadIdx.x;
  const int lane = tid & 63;
  const int w = tid >> 6;
  const int wr = w >> 1, wc = w & 1;
  const int row0 = blockIdx.y * 128;
  const int col0 = blockIdx.x * 128;
  const int lr = lane & 15;
  const int g = lane >> 4;

  const int o0 = w * 1024 + lane * 16;
  const int o1 = o0 + 4096;
  const int r0s = o0 >> 6, c0s = (o0 & 63) >> 1;
  const int r1s = o1 >> 6, c1s = (o1 & 63) >> 1;
  const int l0 = (w * 1024) >> 1;
  const int l1 = l0 + 2048;
  const uint16_t* Abase = A + (size_t)row0 * K;
  const uint16_t* Wbase = W + (size_t)col0 * K;

  auto stage = [&](int kt) {
    uint16_t* Ad = &As[kt & 1][0];
    uint16_t* Bd = &Bs[kt & 1][0];
    const int kk = kt * 32;
    gload16(Abase + (size_t)r0s * K + kk + c0s, Ad + l0);
    gload16(Abase + (size_t)r1s * K + kk + c1s, Ad + l1);
    gload16(Wbase + (size_t)r0s * K + kk + c0s, Bd + l0);
    gload16(Wbase + (size_t)r1s * K + kk + c1s, Bd + l1);
  };

  f32x4 acc[4][4] = {};
  const int nt = K >> 5;
  stage(0);
  for (int kt = 0; kt < nt; ++kt) {
    if (kt + 1 < nt) {
      stage(kt + 1);
      asm volatile("s_waitcnt vmcnt(4)" ::: "memory");
    } else {
      asm volatile("s_waitcnt vmcnt(0)" ::: "memory");
    }
    __builtin_amdgcn_s_barrier();
    MEMFENCE;
    const uint16_t* Ab = &As[kt & 1][0];
    const uint16_t* Bb = &Bs[kt & 1][0];
    bf16x8 a[4], b[4];
#pragma unroll
    for (int m = 0; m < 4; ++m) a[m] = ldb8(Ab + (wr * 64 + m * 16 + lr) * 32 + g * 8);
#pragma unroll
    for (int n = 0; n < 4; ++n) b[n] = ldb8(Bb + (wc * 64 + n * 16 + lr) * 32 + g * 8);
#pragma unroll
    for (int m = 0; m < 4; ++m)
#pragma unroll
      for (int n = 0; n < 4; ++n)
        acc[m][n] = __builtin_amdgcn_mfma_f32_16x16x32_bf16(a[m], b[n], acc[m][n], 0, 0, 0);
    MEMFENCE;
    __builtin_amdgcn_s_barrier();
  }

#pragma unroll
  for (int m = 0; m < 4; ++m) {
    int row = row0 + wr * 64 + m * 16 + g * 4;
#pragma unroll
    for (int n = 0; n < 4; ++n) {
      int col = col0 + wc * 64 + n * 16 + lr;
      float bv = bias[col];
#pragma unroll
      for (int ri = 0; ri < 4; ++ri) {
        float val = acc[m][n][ri] + bv;
        size_t idx = (size_t)(row + ri) * N + col;
        if constexpr (MODE == 0) {
          if (col < DMODEL) val *= QSCALE;   // fold attn scale + log2e into Q
          ((uint16_t*)outp)[idx] = f2bf(val);
        } else {
          float ge = 0.5f * val * (1.0f + erff(val * 0.70710678118654752f));
          ((uint16_t*)outp)[idx] = f2bf(ge);
        }
      }
    }
  }
}

// ------------- GEMM B v2: 64x64 tile, BK=64, 4 waves (2x2, wave=32x32) ---------
// XOR-swizzled LDS (row stride 128B); grid (N/64, M/64) = 768 blocks = 3/CU,
// 12 waves/CU. out f32 = resid + gamma*(acc+bias).
__global__ __launch_bounds__(256, 3) void gemm64(const uint16_t* __restrict__ A,
                                                 const uint16_t* __restrict__ W,
                                                 const float* __restrict__ bias,
                                                 float* __restrict__ outp,
                                                 const float* __restrict__ resid,
                                                 const float* __restrict__ gamma,
                                                 int M, int N, int K) {
  __shared__ uint16_t As[2][64 * 64];
  __shared__ uint16_t Bs[2][64 * 64];
  const int tid = threadIdx.x;
  const int lane = tid & 63;
  const int w = tid >> 6;
  const int wr = w >> 1, wc = w & 1;
  const int row0 = blockIdx.y * 64;
  const int col0 = blockIdx.x * 64;
  const int lr = lane & 15;
  const int g = lane >> 4;

  // staging: issue i covers rows i*32+(tid>>3), chunk tid&7; source pre-swizzled
  const int srow = tid >> 3;
  const int schunk = tid & 7;
  const uint16_t* Abase = A + (size_t)row0 * K;
  const uint16_t* Wbase = W + (size_t)col0 * K;

  auto stage = [&](int kt) {
    uint16_t* Ad = &As[kt & 1][0];
    uint16_t* Bd = &Bs[kt & 1][0];
    const int kk = kt * 64;
#pragma unroll
    for (int i = 0; i < 2; ++i) {
      const int row = i * 32 + srow;
      const int sc = (schunk ^ (row & 7)) * 8;
      gload16(Abase + (size_t)row * K + kk + sc, Ad + i * 2048 + w * 512);
      gload16(Wbase + (size_t)row * K + kk + sc, Bd + i * 2048 + w * 512);
    }
  };

  f32x4 acc[2][2] = {};
  const int nt = K >> 6;
  stage(0);
  for (int kt = 0; kt < nt; ++kt) {
    if (kt + 1 < nt) {
      stage(kt + 1);
      asm volatile("s_waitcnt vmcnt(4)" ::: "memory");
    } else {
      asm volatile("s_waitcnt vmcnt(0)" ::: "memory");
    }
    __builtin_amdgcn_s_barrier();
    MEMFENCE;
    const uint16_t* Ab = &As[kt & 1][0];
    const uint16_t* Bb = &Bs[kt & 1][0];
#pragma unroll
    for (int kk = 0; kk < 2; ++kk) {
      bf16x8 a[2], bf[2];
#pragma unroll
      for (int m = 0; m < 2; ++m) {
        const int row = wr * 32 + m * 16 + lr;
        a[m] = ldb8(Ab + row * 64 + (((kk * 4 + g) ^ (row & 7)) * 8));
      }
#pragma unroll
      for (int n = 0; n < 2; ++n) {
        const int row = wc * 32 + n * 16 + lr;
        bf[n] = ldb8(Bb + row * 64 + (((kk * 4 + g) ^ (row & 7)) * 8));
      }
#pragma unroll
      for (int m = 0; m < 2; ++m)
#pragma unroll
        for (int n = 0; n < 2; ++n)
          acc[m][n] = __builtin_amdgcn_mfma_f32_16x16x32_bf16(a[m], bf[n], acc[m][n], 0, 0, 0);
    }
    MEMFENCE;
    __builtin_amdgcn_s_barrier();
  }

#pragma unroll
  for (int m = 0; m < 2; ++m) {
    int row = row0 + wr * 32 + m * 16 + g * 4;
#pragma unroll
    for (int n = 0; n < 2; ++n) {
      int col = col0 + wc * 32 + n * 16 + lr;
      float bv = bias[col];
      float gv = gamma[col];
#pragma unroll
      for (int ri = 0; ri < 4; ++ri) {
        float val = acc[m][n][ri] + bv;
        size_t idx = (size_t)(row + ri) * N + col;
        outp[idx] = resid[idx] + gv * val;
      }
    }
  }
}

// ---------------- prep: masked-K copy + masked-V transpose ---------------------
__global__ __launch_bounds__(256) void prep_kernel(const uint16_t* __restrict__ qkv,
                                                   const int* __restrict__ mask,
                                                   uint16_t* __restrict__ km,
                                                   uint16_t* __restrict__ vt) {
  __shared__ uint16_t tile[64][72];
  const int t = threadIdx.x;
  const int bh = blockIdx.x;
  const int n0 = blockIdx.y * 64;
  const int b = bh / NHEAD, h = bh % NHEAD;
  const int* mb = mask + b * NSEQ;
  const uint16_t* src = qkv + (size_t)(b * NSEQ + n0) * (3 * DMODEL) + h * HDIM;
  uint16_t* kdst = km + (size_t)(b * NSEQ + n0) * DMODEL + h * HDIM;
#pragma unroll
  for (int it = 0; it < 2; ++it) {
    int slot = it * 256 + t;
    int r = slot >> 2, c = (slot & 3) * 16;
    uint16_t mz = (mb[n0 + r] != 0) ? (uint16_t)0xFFFF : (uint16_t)0;
    const uint16_t* rp = src + (size_t)r * (3 * DMODEL);
    u16x8 k0 = *reinterpret_cast<const u16x8*>(rp + DMODEL + c) & mz;
    u16x8 k1 = *reinterpret_cast<const u16x8*>(rp + DMODEL + c + 8) & mz;
    u16x8 v0 = *reinterpret_cast<const u16x8*>(rp + 2 * DMODEL + c) & mz;
    u16x8 v1 = *reinterpret_cast<const u16x8*>(rp + 2 * DMODEL + c + 8) & mz;
    *reinterpret_cast<u16x8*>(kdst + (size_t)r * DMODEL + c) = k0;
    *reinterpret_cast<u16x8*>(kdst + (size_t)r * DMODEL + c + 8) = k1;
    *reinterpret_cast<u16x8*>(&tile[r][c]) = v0;
    *reinterpret_cast<u16x8*>(&tile[r][c + 8]) = v1;
  }
  __syncthreads();
  uint16_t* dst = vt + (size_t)bh * HDIM * NSEQ + n0;
#pragma unroll
  for (int it = 0; it < 2; ++it) {
    int slot = it * 256 + t;
    int d = slot >> 2, c = (slot & 3) * 16;
    u16x8 a0, a1;
#pragma unroll
    for (int e = 0; e < 8; ++e) a0[e] = tile[c + e][d];
#pragma unroll
    for (int e = 0; e < 8; ++e) a1[e] = tile[c + 8 + e][d];
    *reinterpret_cast<u16x8*>(dst + (size_t)d * NSEQ + c) = a0;
    *reinterpret_cast<u16x8*>(dst + (size_t)d * NSEQ + c + 8) = a1;
  }
}

// ---------------- flash attention v6: split-KV, maskless exp2, ones-MFMA lsum --
// grid (24,16,2): 4 waves x 32 q-rows. Row-sum on the matrix pipe (lacc regs,
// D-layout rows = q) + scalar corr accumulator for masked-key junk.
__global__ __launch_bounds__(256, 3) void attn_kernel(const uint16_t* __restrict__ qkv,
                                                      const uint16_t* __restrict__ km,
                                                      const uint16_t* __restrict__ vt,
                                                      const int* __restrict__ mask,
                                                      uint16_t* __restrict__ po,
                                                      float* __restrict__ pml) {
  __shared__ uint16_t Kb[2][64 * 64];
  __shared__ uint16_t Vb[2][64 * 64];
  __shared__ unsigned long long mbits[16];
  const int tid = threadIdx.x;
  const int lane = tid & 63;
  const int w = tid >> 6;
  const int bh = blockIdx.x;
  const int b = bh / NHEAD, hd = bh % NHEAD;
  const int z = blockIdx.z;
  const int kbase = z * 1024;
  const int q0 = blockIdx.y * 128 + w * 32;
  const int l31 = lane & 31;
  const int hh = lane >> 5;

  const int* mb = mask + b * NSEQ;
#pragma unroll
  for (int it = 0; it < 4; ++it) {
    unsigned long long bm = __ballot(mb[kbase + it * 256 + tid] != 0);
    if (lane == 0) mbits[it * 4 + w] = bm;
  }

  bf16x8 qa[4];
  const uint16_t* qptr = qkv + (size_t)(b * NSEQ + q0 + l31) * (3 * DMODEL) + hd * HDIM + hh * 8;
#pragma unroll
  for (int dblk = 0; dblk < 4; ++dblk) qa[dblk] = ldb8(qptr + dblk * 16);

  const uint16_t* kmb = km + (size_t)b * NSEQ * DMODEL + hd * HDIM;
  const uint16_t* vtb = vt + (size_t)bh * HDIM * NSEQ;

  __syncthreads();   // mbits visible

  const int srow = tid >> 3;
  const int sxor = ((tid & 7) ^ (srow & 7)) * 8;
  auto stage = [&](int t) {
    const int pb = t & 1;
    const int k0 = kbase + t * 64;
#pragma unroll
    for (int i = 0; i < 2; ++i) {
      const int row = i * 32 + srow;
      gload16(kmb + (size_t)(k0 + row) * DMODEL + sxor, &Kb[pb][i * 2048 + w * 512]);
      gload16(vtb + (size_t)row * NSEQ + k0 + sxor, &Vb[pb][i * 2048 + w * 512]);
    }
  };

  u16x8 ones_u;
#pragma unroll
  for (int e = 0; e < 8; ++e) ones_u[e] = 0x3F80;   // bf16 1.0
  const bf16x8 ones = __builtin_bit_cast(bf16x8, ones_u);

  float m_ = 0.f, corr = 0.f;        // inflated-max start (masked scores == 0)
  f32x16 oacc[2] = {};
  f32x16 lacc = {};                  // row-sum accumulator (regs = q rows)

  stage(0);
  for (int t = 0; t < 16; ++t) {
    if (t + 1 < 16) {
      stage(t + 1);
      asm volatile("s_waitcnt vmcnt(4)" ::: "memory");
    } else {
      asm volatile("s_waitcnt vmcnt(0)" ::: "memory");
    }
    __builtin_amdgcn_s_barrier();
    MEMFENCE;
    const uint16_t* Kbp = &Kb[t & 1][0];
    const uint16_t* Vbp = &Vb[t & 1][0];

    // S^T[k][q] = mfma(K, Q); lane = q, regs = k
    f32x16 st[2];
    __builtin_amdgcn_s_setprio(1);
#pragma unroll
    for (int kblk = 0; kblk < 2; ++kblk) {
      f32x16 acc = {};
      const uint16_t* kr = Kbp + (kblk * 32 + l31) * 64;
#pragma unroll
      for (int dblk = 0; dblk < 4; ++dblk) {
        bf16x8 kf = ldb8(kr + ((dblk * 2 + hh) ^ (l31 & 7)) * 8);
        acc = __builtin_amdgcn_mfma_f32_32x32x16_bf16(kf, qa[dblk], acc, 0, 0, 0);
      }
      st[kblk] = acc;
    }
    __builtin_amdgcn_s_setprio(0);

    // row max (max3-friendly pairs)
    float tm = fmaxf(st[0][0], st[0][1]);
#pragma unroll
    for (int r = 2; r < 16; r += 2) tm = fmaxf(fmaxf(tm, st[0][r]), st[0][r + 1]);
#pragma unroll
    for (int r = 0; r < 16; r += 2) tm = fmaxf(fmaxf(tm, st[1][r]), st[1][r + 1]);
    tm = fmaxf(tm, __shfl_xor(tm, 32));
    if (__any(tm - m_ > 16.0f)) {      // defer-max, log2 units
      float mn = fmaxf(m_, tm);
      float al = exp2f(m_ - mn);
      corr *= al;
      m_ = mn;
      float ar[16];
#pragma unroll
      for (int r = 0; r < 16; ++r)
        ar[r] = __shfl(al, (r & 3) + 8 * (r >> 2) + 4 * hh);
#pragma unroll
      for (int r = 0; r < 16; ++r) {
        oacc[0][r] *= ar[r];
        oacc[1][r] *= ar[r];
        lacc[r] *= ar[r];
      }
    }

    // exp2 + pack (no per-element sum: row-sum goes to matrix pipe)
    uint32_t pk[2][8];
#pragma unroll
    for (int kblk = 0; kblk < 2; ++kblk)
#pragma unroll
      for (int wn = 0; wn < 8; ++wn) {
        float e0 = exp2f(st[kblk][2 * wn] - m_);
        float e1 = exp2f(st[kblk][2 * wn + 1] - m_);
        pk[kblk][wn] = (uint32_t)f2bf(e0) | ((uint32_t)f2bf(e1) << 16);
      }
    // masked-key junk accumulator (each masked k contributes exp2(0 - m_))
    const unsigned long long wb = mbits[t];
    corr += (float)(64 - __popcll(wb)) * exp2f(0.f - m_);

    // gather PV A-frags
    bf16x8 af[4];
#pragma unroll
    for (int kb16 = 0; kb16 < 4; ++kb16) {
      const int kblk = kb16 >> 1;
      const int a4 = (kb16 & 1) * 4;
      uint32_t ow0 = hh ? pk[kblk][a4 + 2] : pk[kblk][a4 + 0];
      uint32_t ow1 = hh ? pk[kblk][a4 + 3] : pk[kblk][a4 + 1];
      uint32_t gv0 = hh ? pk[kblk][a4 + 0] : pk[kblk][a4 + 2];
      uint32_t gv1 = hh ? pk[kblk][a4 + 1] : pk[kblk][a4 + 3];
      uint32_t sw0 = (uint32_t)__shfl_xor((int)gv0, 32);
      uint32_t sw1 = (uint32_t)__shfl_xor((int)gv1, 32);
      u32x4 afu;
      afu[0] = hh ? sw0 : ow0;
      afu[1] = hh ? sw1 : ow1;
      afu[2] = hh ? ow0 : sw0;
      afu[3] = hh ? ow1 : sw1;
      af[kb16] = __builtin_bit_cast(bf16x8, afu);
    }

    __builtin_amdgcn_s_setprio(1);
#pragma unroll
    for (int dblk = 0; dblk < 2; ++dblk) {
      const uint16_t* vr = Vbp + (dblk * 32 + l31) * 64;
#pragma unroll
      for (int kb16 = 0; kb16 < 4; ++kb16) {
        bf16x8 vf = ldb8(vr + ((kb16 * 2 + hh) ^ (l31 & 7)) * 8);
        oacc[dblk] = __builtin_amdgcn_mfma_f32_32x32x16_bf16(af[kb16], vf, oacc[dblk], 0, 0, 0);
      }
    }
#pragma unroll
    for (int kb16 = 0; kb16 < 4; ++kb16)   // row-sum on matrix pipe
      lacc = __builtin_amdgcn_mfma_f32_32x32x16_bf16(af[kb16], ones, lacc, 0, 0, 0);
    __builtin_amdgcn_s_setprio(0);
    MEMFENCE;
    __builtin_amdgcn_s_barrier();
  }

  // write unnormalized partial O (bf16)
  uint16_t* ob = po + ((size_t)z * PROWS + (size_t)bh * NSEQ + q0) * 64;
#pragma unroll
  for (int r = 0; r < 16; ++r) {
    const int qrow = (r & 3) + 8 * (r >> 2) + 4 * hh;
#pragma unroll
    for (int dblk = 0; dblk < 2; ++dblk)
      ob[(size_t)qrow * 64 + dblk * 32 + l31] = f2bf(oacc[dblk][r]);
  }
  // write (m, denom) per q-row
#pragma unroll
  for (int r = 0; r < 16; ++r) {
    const int qrow = (r & 3) + 8 * (r >> 2) + 4 * hh;
    float mr = __shfl(m_, qrow);
    float cr = __shfl(corr, qrow);
    float dr = lacc[r] - cr;
    if (l31 == 0)
      *(float2*)(pml + ((size_t)z * PROWS + (size_t)bh * NSEQ + q0 + qrow) * 2) =
          make_float2(mr, dr);
  }
}

// ---------------- merge split-KV partials -> o_bf ------------------------------
__global__ __launch_bounds__(256) void merge_kernel(const uint16_t* __restrict__ po,
                                                    const float* __restrict__ pml,
                                                    uint16_t* __restrict__ o) {
  int gid = blockIdx.x * 256 + threadIdx.x;   // 393216 = 49152 rows x 8 chunks
  int row = gid >> 3;
  int c0 = (gid & 7) * 8;
  float m1 = pml[(size_t)row * 2], l1 = pml[(size_t)row * 2 + 1];
  float m2 = pml[((size_t)PROWS + row) * 2], l2 = pml[((size_t)PROWS + row) * 2 + 1];
  float M = fmaxf(m1, m2);
  float w1 = exp2f(m1 - M), w2 = exp2f(m2 - M);
  float L = w1 * l1 + w2 * l2;
  float inv = L > 0.f ? 1.f / L : 0.f;
  w1 *= inv; w2 *= inv;
  u16x8 a = *reinterpret_cast<const u16x8*>(po + (size_t)row * 64 + c0);
  u16x8 b = *reinterpret_cast<const u16x8*>(po + ((size_t)PROWS + row) * 64 + c0);
  int bh = row >> 11, q = row & 2047;
  int bb = bh / NHEAD, hh = bh % NHEAD;
  uint16_t* op = o + ((size_t)(bb * NSEQ + q) * DMODEL + hh * HDIM + c0);
  u16x8 outv;
#pragma unroll
  for (int e = 0; e < 8; ++e)
    outv[e] = f2bf(w1 * bf2f(a[e]) + w2 * bf2f(b[e]));
  *reinterpret_cast<u16x8*>(op) = outv;
}

// ---------------- host ----------------
extern "C" void kernel_launch(void* const* d_in, const int* in_sizes, int n_in,
                              void* d_out, int out_size, void* d_ws, size_t ws_size,
                              hipStream_t stream) {
  const float* x      = (const float*)d_in[0];
  const int*   amask  = (const int*)d_in[1];
  const float* ln1_g  = (const float*)d_in[2];
  const float* ln1_b  = (const float*)d_in[3];
  const float* qkv_w  = (const float*)d_in[4];
  const float* q_bias = (const float*)d_in[5];
  const float* v_bias = (const float*)d_in[6];
  const float* proj_w = (const float*)d_in[7];
  const float* proj_b = (const float*)d_in[8];
  const float* ln2_g  = (const float*)d_in[9];
  const float* ln2_b  = (const float*)d_in[10];
  const float* fc1_w  = (const float*)d_in[11];
  const float* fc1_b  = (const float*)d_in[12];
  const float* fc2_w  = (const float*)d_in[13];
  const float* fc2_b  = (const float*)d_in[14];
  const float* g1     = (const float*)d_in[15];
  const float* g2     = (const float*)d_in[16];

  char* ws = (char*)d_ws;
  uint16_t* qkvw_bf  = (uint16_t*)(ws + 0);
  uint16_t* projw_bf = (uint16_t*)(ws + 3538944);
  uint16_t* fc1w_bf  = (uint16_t*)(ws + 4718592);
  uint16_t* fc2w_bf  = (uint16_t*)(ws + 9437184);
  float*    qkvbias  = (float*)(ws + 14155776);
  uint16_t* h_bf     = (uint16_t*)(ws + 14164992);
  uint16_t* km       = h_bf;                         // masked-K alias
  uint16_t* h2_bf    = h_bf;                         // ln2 out (after attn)
  uint16_t* qkv_bf   = (uint16_t*)(ws + 20456448);
  uint16_t* vt_bf    = (uint16_t*)(ws + 39330816);
  uint16_t* o_bf     = (uint16_t*)(ws + 45622272);
  float*    x1_f     = (float*)(ws + 51913728);
  uint16_t* po       = (uint16_t*)(ws + 51913728);   // partials alias x1_f
  float*    pml      = (float*)(ws + 64496640);
  uint16_t* fc1_bf   = qkv_bf;

  const int M = BATCH * NSEQ;

  cvt4_kernel<<<(N_QKVW + N_PROJW + N_FC1W + N_FC2W) / 1024, 256, 0, stream>>>(
      qkv_w, proj_w, fc1_w, fc2_w, qkvw_bf, projw_bf, fc1w_bf, fc2w_bf);
  bias_kernel<<<(3 * DMODEL + 255) / 256, 256, 0, stream>>>(q_bias, v_bias, qkvbias);

  ln_kernel<<<M, 256, 0, stream>>>(x, ln1_g, ln1_b, h_bf);
  gemm128<0><<<dim3((3 * DMODEL) / 128, M / 128), 256, 0, stream>>>(
      h_bf, qkvw_bf, qkvbias, qkv_bf, M, 3 * DMODEL, DMODEL);
  prep_kernel<<<dim3(BATCH * NHEAD, NSEQ / 64), 256, 0, stream>>>(qkv_bf, amask, km, vt_bf);
  attn_kernel<<<dim3(BATCH * NHEAD, NSEQ / 128, 2), 256, 0, stream>>>(
      qkv_bf, km, vt_bf, amask, po, pml);
  merge_kernel<<<(PROWS * 8) / 256, 256, 0, stream>>>(po, pml, o_bf);
  gemm64<<<dim3(DMODEL / 64, M / 64), 256, 0, stream>>>(
      o_bf, projw_bf, proj_b, x1_f, x, g1, M, DMODEL, DMODEL);
  ln_kernel<<<M, 256, 0, stream>>>(x1_f, ln2_g, ln2_b, h2_bf);
  gemm128<2><<<dim3(HIDDEN / 128, M / 128), 256, 0, stream>>>(
      h2_bf, fc1w_bf, fc1_b, fc1_bf, M, HIDDEN, DMODEL);
  gemm64<<<dim3(DMODEL / 64, M / 64), 256, 0, stream>>>(
      fc1_bf, fc2w_bf, fc2_b, (float*)d_out, x1_f, g2, M, DMODEL, HIDDEN);
}

// Round 9
// 195.235 us; speedup vs baseline: 1.3199x; 1.0383x over previous
//
#include <hip/hip_runtime.h>
#include <hip/hip_bf16.h>
#include <stdint.h>

// ---------------- types / helpers ----------------
typedef __bf16 bf16x8 __attribute__((ext_vector_type(8)));
typedef __bf16 bf16x2 __attribute__((ext_vector_type(2)));
typedef unsigned short u16x8 __attribute__((ext_vector_type(8)));
typedef float f32x4 __attribute__((ext_vector_type(4)));
typedef float f32x16 __attribute__((ext_vector_type(16)));
typedef uint32_t u32x4 __attribute__((ext_vector_type(4)));

#define DMODEL 768
#define NSEQ   2048
#define BATCH  2
#define NHEAD  12
#define HDIM   64
#define HIDDEN 3072
#define PROWS  (BATCH * NHEAD * NSEQ)   // 49152 attention rows
// 0.125 * log2(e): fold softmax scale AND exp->exp2 conversion into Q
#define QSCALE 0.18033688011112042f
#define MCONST 16.0f                    // constant softmax max (scores << 16)
#define PMASKED 1.52587890625e-05f      // exp2(0 - 16): each masked key's P

__device__ __forceinline__ uint16_t f2bf(float f) {
  __bf16 h = (__bf16)f;                 // native RNE cast (v_cvt)
  return __builtin_bit_cast(uint16_t, h);
}
__device__ __forceinline__ float bf2f(uint16_t u) {
  uint32_t x = (uint32_t)u << 16;
  return __builtin_bit_cast(float, x);
}
__device__ __forceinline__ bf16x8 ldb8(const uint16_t* p) {
  return __builtin_bit_cast(bf16x8, *reinterpret_cast<const u16x8*>(p));
}

using as1_void = __attribute__((address_space(1))) const void;
using as3_void = __attribute__((address_space(3))) void;
__device__ __forceinline__ void gload16(const uint16_t* src, uint16_t* lds) {
  __builtin_amdgcn_global_load_lds((as1_void*)src, (as3_void*)lds, 16, 0, 0);
}
#define MEMFENCE asm volatile("" ::: "memory")

// ---------------- fused fp32 -> bf16 casts ----------------
#define N_QKVW  (3 * DMODEL * DMODEL)
#define N_PROJW (DMODEL * DMODEL)
#define N_FC1W  (HIDDEN * DMODEL)
#define N_FC2W  (DMODEL * HIDDEN)
__global__ __launch_bounds__(256) void cvt4_kernel(const float* __restrict__ s0,
                                                   const float* __restrict__ s1,
                                                   const float* __restrict__ s2,
                                                   const float* __restrict__ s3,
                                                   uint16_t* __restrict__ d0,
                                                   uint16_t* __restrict__ d1,
                                                   uint16_t* __restrict__ d2,
                                                   uint16_t* __restrict__ d3) {
  int i4 = (blockIdx.x * 256 + threadIdx.x) * 4;
  const float* s;
  uint16_t* d;
  if (i4 < N_QKVW) { s = s0 + i4; d = d0 + i4; }
  else if (i4 < N_QKVW + N_PROJW) { int j = i4 - N_QKVW; s = s1 + j; d = d1 + j; }
  else if (i4 < N_QKVW + N_PROJW + N_FC1W) { int j = i4 - N_QKVW - N_PROJW; s = s2 + j; d = d2 + j; }
  else { int j = i4 - N_QKVW - N_PROJW - N_FC1W; s = s3 + j; d = d3 + j; }
  float4 v = *reinterpret_cast<const float4*>(s);
  ushort4 o;
  o.x = f2bf(v.x); o.y = f2bf(v.y); o.z = f2bf(v.z); o.w = f2bf(v.w);
  *reinterpret_cast<ushort4*>(d) = o;
}

// ---------------- qkv bias assembly ----------------
__global__ __launch_bounds__(256) void bias_kernel(const float* __restrict__ qb,
                                                   const float* __restrict__ vb,
                                                   float* __restrict__ out) {
  int j = blockIdx.x * 256 + threadIdx.x;
  if (j < 3 * DMODEL) {
    float v = 0.f;
    if (j < DMODEL) v = qb[j];
    else if (j >= 2 * DMODEL) v = vb[j - 2 * DMODEL];
    out[j] = v;
  }
}

// ---------------- layernorm: fp32 in -> bf16 out ----------------
__global__ __launch_bounds__(256) void ln_kernel(const float* __restrict__ x,
                                                 const float* __restrict__ g,
                                                 const float* __restrict__ bt,
                                                 uint16_t* __restrict__ out) {
  const int row = blockIdx.x;
  const int t = threadIdx.x;
  const float* xr = x + (size_t)row * DMODEL;
  float v0 = xr[t], v1 = xr[t + 256], v2 = xr[t + 512];
  float s = v0 + v1 + v2;
  float q = v0 * v0 + v1 * v1 + v2 * v2;
  for (int off = 32; off >= 1; off >>= 1) {
    s += __shfl_xor(s, off);
    q += __shfl_xor(q, off);
  }
  __shared__ float ss[4], sq[4];
  int w = t >> 6;
  if ((t & 63) == 0) { ss[w] = s; sq[w] = q; }
  __syncthreads();
  s = ss[0] + ss[1] + ss[2] + ss[3];
  q = sq[0] + sq[1] + sq[2] + sq[3];
  const float mean = s * (1.0f / DMODEL);
  const float var = q * (1.0f / DMODEL) - mean * mean;
  const float rstd = rsqrtf(var + 1e-5f);
  uint16_t* orow = out + (size_t)row * DMODEL;
  orow[t]       = f2bf((v0 - mean) * rstd * g[t]       + bt[t]);
  orow[t + 256] = f2bf((v1 - mean) * rstd * g[t + 256] + bt[t + 256]);
  orow[t + 512] = f2bf((v2 - mean) * rstd * g[t + 512] + bt[t + 512]);
}

// ------------- GEMM A: 128x128 block, 4 waves x (64x64), dbuf counted-vmcnt ----
template <int MODE>
__global__ __launch_bounds__(256, 3) void gemm128(const uint16_t* __restrict__ A,
                                                  const uint16_t* __restrict__ W,
                                                  const float* __restrict__ bias,
                                                  void* __restrict__ outp,
                                                  int M, int N, int K) {
  __shared__ uint16_t As[2][128 * 32];
  __shared__ uint16_t Bs[2][128 * 32];
  const int tid = threadIdx.x;
  const int lane = tid & 63;
  const int w = tid >> 6;
  const int wr = w >> 1, wc = w & 1;
  const int row0 = blockIdx.y * 128;
  const int col0 = blockIdx.x * 128;
  const int lr = lane & 15;
  const int g = lane >> 4;

  const int o0 = w * 1024 + lane * 16;
  const int o1 = o0 + 4096;
  const int r0s = o0 >> 6, c0s = (o0 & 63) >> 1;
  const int r1s = o1 >> 6, c1s = (o1 & 63) >> 1;
  const int l0 = (w * 1024) >> 1;
  const int l1 = l0 + 2048;
  const uint16_t* Abase = A + (size_t)row0 * K;
  const uint16_t* Wbase = W + (size_t)col0 * K;

  auto stage = [&](int kt) {
    uint16_t* Ad = &As[kt & 1][0];
    uint16_t* Bd = &Bs[kt & 1][0];
    const int kk = kt * 32;
    gload16(Abase + (size_t)r0s * K + kk + c0s, Ad + l0);
    gload16(Abase + (size_t)r1s * K + kk + c1s, Ad + l1);
    gload16(Wbase + (size_t)r0s * K + kk + c0s, Bd + l0);
    gload16(Wbase + (size_t)r1s * K + kk + c1s, Bd + l1);
  };

  f32x4 acc[4][4] = {};
  const int nt = K >> 5;
  stage(0);
  for (int kt = 0; kt < nt; ++kt) {
    if (kt + 1 < nt) {
      stage(kt + 1);
      asm volatile("s_waitcnt vmcnt(4)" ::: "memory");
    } else {
      asm volatile("s_waitcnt vmcnt(0)" ::: "memory");
    }
    __builtin_amdgcn_s_barrier();
    MEMFENCE;
    const uint16_t* Ab = &As[kt & 1][0];
    const uint16_t* Bb = &Bs[kt & 1][0];
    bf16x8 a[4], b[4];
#pragma unroll
    for (int m = 0; m < 4; ++m) a[m] = ldb8(Ab + (wr * 64 + m * 16 + lr) * 32 + g * 8);
#pragma unroll
    for (int n = 0; n < 4; ++n) b[n] = ldb8(Bb + (wc * 64 + n * 16 + lr) * 32 + g * 8);
#pragma unroll
    for (int m = 0; m < 4; ++m)
#pragma unroll
      for (int n = 0; n < 4; ++n)
        acc[m][n] = __builtin_amdgcn_mfma_f32_16x16x32_bf16(a[m], b[n], acc[m][n], 0, 0, 0);
    MEMFENCE;
    __builtin_amdgcn_s_barrier();
  }

#pragma unroll
  for (int m = 0; m < 4; ++m) {
    int row = row0 + wr * 64 + m * 16 + g * 4;
#pragma unroll
    for (int n = 0; n < 4; ++n) {
      int col = col0 + wc * 64 + n * 16 + lr;
      float bv = bias[col];
#pragma unroll
      for (int ri = 0; ri < 4; ++ri) {
        float val = acc[m][n][ri] + bv;
        size_t idx = (size_t)(row + ri) * N + col;
        if constexpr (MODE == 0) {
          if (col < DMODEL) val *= QSCALE;   // fold attn scale + log2e into Q
          ((uint16_t*)outp)[idx] = f2bf(val);
        } else {
          float ge = 0.5f * val * (1.0f + erff(val * 0.70710678118654752f));
          ((uint16_t*)outp)[idx] = f2bf(ge);
        }
      }
    }
  }
}

// ------------- GEMM B v2: 64x64 tile, BK=64, 4 waves (2x2, wave=32x32) ---------
__global__ __launch_bounds__(256, 3) void gemm64(const uint16_t* __restrict__ A,
                                                 const uint16_t* __restrict__ W,
                                                 const float* __restrict__ bias,
                                                 float* __restrict__ outp,
                                                 const float* __restrict__ resid,
                                                 const float* __restrict__ gamma,
                                                 int M, int N, int K) {
  __shared__ uint16_t As[2][64 * 64];
  __shared__ uint16_t Bs[2][64 * 64];
  const int tid = threadIdx.x;
  const int lane = tid & 63;
  const int w = tid >> 6;
  const int wr = w >> 1, wc = w & 1;
  const int row0 = blockIdx.y * 64;
  const int col0 = blockIdx.x * 64;
  const int lr = lane & 15;
  const int g = lane >> 4;

  const int srow = tid >> 3;
  const int schunk = tid & 7;
  const uint16_t* Abase = A + (size_t)row0 * K;
  const uint16_t* Wbase = W + (size_t)col0 * K;

  auto stage = [&](int kt) {
    uint16_t* Ad = &As[kt & 1][0];
    uint16_t* Bd = &Bs[kt & 1][0];
    const int kk = kt * 64;
#pragma unroll
    for (int i = 0; i < 2; ++i) {
      const int row = i * 32 + srow;
      const int sc = (schunk ^ (row & 7)) * 8;
      gload16(Abase + (size_t)row * K + kk + sc, Ad + i * 2048 + w * 512);
      gload16(Wbase + (size_t)row * K + kk + sc, Bd + i * 2048 + w * 512);
    }
  };

  f32x4 acc[2][2] = {};
  const int nt = K >> 6;
  stage(0);
  for (int kt = 0; kt < nt; ++kt) {
    if (kt + 1 < nt) {
      stage(kt + 1);
      asm volatile("s_waitcnt vmcnt(4)" ::: "memory");
    } else {
      asm volatile("s_waitcnt vmcnt(0)" ::: "memory");
    }
    __builtin_amdgcn_s_barrier();
    MEMFENCE;
    const uint16_t* Ab = &As[kt & 1][0];
    const uint16_t* Bb = &Bs[kt & 1][0];
#pragma unroll
    for (int kk = 0; kk < 2; ++kk) {
      bf16x8 a[2], bf[2];
#pragma unroll
      for (int m = 0; m < 2; ++m) {
        const int row = wr * 32 + m * 16 + lr;
        a[m] = ldb8(Ab + row * 64 + (((kk * 4 + g) ^ (row & 7)) * 8));
      }
#pragma unroll
      for (int n = 0; n < 2; ++n) {
        const int row = wc * 32 + n * 16 + lr;
        bf[n] = ldb8(Bb + row * 64 + (((kk * 4 + g) ^ (row & 7)) * 8));
      }
#pragma unroll
      for (int m = 0; m < 2; ++m)
#pragma unroll
        for (int n = 0; n < 2; ++n)
          acc[m][n] = __builtin_amdgcn_mfma_f32_16x16x32_bf16(a[m], bf[n], acc[m][n], 0, 0, 0);
    }
    MEMFENCE;
    __builtin_amdgcn_s_barrier();
  }

#pragma unroll
  for (int m = 0; m < 2; ++m) {
    int row = row0 + wr * 32 + m * 16 + g * 4;
#pragma unroll
    for (int n = 0; n < 2; ++n) {
      int col = col0 + wc * 32 + n * 16 + lr;
      float bv = bias[col];
      float gv = gamma[col];
#pragma unroll
      for (int ri = 0; ri < 4; ++ri) {
        float val = acc[m][n][ri] + bv;
        size_t idx = (size_t)(row + ri) * N + col;
        outp[idx] = resid[idx] + gv * val;
      }
    }
  }
}

// ---------------- prep: masked-K copy + masked-V transpose ---------------------
__global__ __launch_bounds__(256) void prep_kernel(const uint16_t* __restrict__ qkv,
                                                   const int* __restrict__ mask,
                                                   uint16_t* __restrict__ km,
                                                   uint16_t* __restrict__ vt) {
  __shared__ uint16_t tile[64][72];
  const int t = threadIdx.x;
  const int bh = blockIdx.x;
  const int n0 = blockIdx.y * 64;
  const int b = bh / NHEAD, h = bh % NHEAD;
  const int* mb = mask + b * NSEQ;
  const uint16_t* src = qkv + (size_t)(b * NSEQ + n0) * (3 * DMODEL) + h * HDIM;
  uint16_t* kdst = km + (size_t)(b * NSEQ + n0) * DMODEL + h * HDIM;
#pragma unroll
  for (int it = 0; it < 2; ++it) {
    int slot = it * 256 + t;
    int r = slot >> 2, c = (slot & 3) * 16;
    uint16_t mz = (mb[n0 + r] != 0) ? (uint16_t)0xFFFF : (uint16_t)0;
    const uint16_t* rp = src + (size_t)r * (3 * DMODEL);
    u16x8 k0 = *reinterpret_cast<const u16x8*>(rp + DMODEL + c) & mz;
    u16x8 k1 = *reinterpret_cast<const u16x8*>(rp + DMODEL + c + 8) & mz;
    u16x8 v0 = *reinterpret_cast<const u16x8*>(rp + 2 * DMODEL + c) & mz;
    u16x8 v1 = *reinterpret_cast<const u16x8*>(rp + 2 * DMODEL + c + 8) & mz;
    *reinterpret_cast<u16x8*>(kdst + (size_t)r * DMODEL + c) = k0;
    *reinterpret_cast<u16x8*>(kdst + (size_t)r * DMODEL + c + 8) = k1;
    *reinterpret_cast<u16x8*>(&tile[r][c]) = v0;
    *reinterpret_cast<u16x8*>(&tile[r][c + 8]) = v1;
  }
  __syncthreads();
  uint16_t* dst = vt + (size_t)bh * HDIM * NSEQ + n0;
#pragma unroll
  for (int it = 0; it < 2; ++it) {
    int slot = it * 256 + t;
    int d = slot >> 2, c = (slot & 3) * 16;
    u16x8 a0, a1;
#pragma unroll
    for (int e = 0; e < 8; ++e) a0[e] = tile[c + e][d];
#pragma unroll
    for (int e = 0; e < 8; ++e) a1[e] = tile[c + 8 + e][d];
    *reinterpret_cast<u16x8*>(dst + (size_t)d * NSEQ + c) = a0;
    *reinterpret_cast<u16x8*>(dst + (size_t)d * NSEQ + c + 8) = a1;
  }
}

// ---------------- flash attention v7: constant-max softmax ---------------------
// grid (24,16,2): 4 waves x 32 q-rows. Masked K rows / V cols pre-zeroed ->
// masked scores exactly 0. Constant m = 16 (scores << 16, f32/bf16 have huge
// headroom) removes the max-reduce chain, defer branch, and per-tile corr:
// P = exp2(s - 16); each masked key contributes exactly 2^-16, corrected once
// at the end via mbits popcounts. Row-sum on the matrix pipe (ones-MFMA).
__global__ __launch_bounds__(256, 3) void attn_kernel(const uint16_t* __restrict__ qkv,
                                                      const uint16_t* __restrict__ km,
                                                      const uint16_t* __restrict__ vt,
                                                      const int* __restrict__ mask,
                                                      uint16_t* __restrict__ po,
                                                      float* __restrict__ pml) {
  __shared__ uint16_t Kb[2][64 * 64];
  __shared__ uint16_t Vb[2][64 * 64];
  __shared__ unsigned long long mbits[16];
  const int tid = threadIdx.x;
  const int lane = tid & 63;
  const int w = tid >> 6;
  const int bh = blockIdx.x;
  const int b = bh / NHEAD, hd = bh % NHEAD;
  const int z = blockIdx.z;
  const int kbase = z * 1024;
  const int q0 = blockIdx.y * 128 + w * 32;
  const int l31 = lane & 31;
  const int hh = lane >> 5;

  const int* mb = mask + b * NSEQ;
#pragma unroll
  for (int it = 0; it < 4; ++it) {
    unsigned long long bm = __ballot(mb[kbase + it * 256 + tid] != 0);
    if (lane == 0) mbits[it * 4 + w] = bm;
  }

  bf16x8 qa[4];
  const uint16_t* qptr = qkv + (size_t)(b * NSEQ + q0 + l31) * (3 * DMODEL) + hd * HDIM + hh * 8;
#pragma unroll
  for (int dblk = 0; dblk < 4; ++dblk) qa[dblk] = ldb8(qptr + dblk * 16);

  const uint16_t* kmb = km + (size_t)b * NSEQ * DMODEL + hd * HDIM;
  const uint16_t* vtb = vt + (size_t)bh * HDIM * NSEQ;

  __syncthreads();   // mbits visible

  const int srow = tid >> 3;
  const int sxor = ((tid & 7) ^ (srow & 7)) * 8;
  auto stage = [&](int t) {
    const int pb = t & 1;
    const int k0 = kbase + t * 64;
#pragma unroll
    for (int i = 0; i < 2; ++i) {
      const int row = i * 32 + srow;
      gload16(kmb + (size_t)(k0 + row) * DMODEL + sxor, &Kb[pb][i * 2048 + w * 512]);
      gload16(vtb + (size_t)row * NSEQ + k0 + sxor, &Vb[pb][i * 2048 + w * 512]);
    }
  };

  u16x8 ones_u;
#pragma unroll
  for (int e = 0; e < 8; ++e) ones_u[e] = 0x3F80;   // bf16 1.0
  const bf16x8 ones = __builtin_bit_cast(bf16x8, ones_u);

  f32x16 oacc[2] = {};
  f32x16 lacc = {};                  // row-sum accumulator (regs = q rows)

  stage(0);
  for (int t = 0; t < 16; ++t) {
    if (t + 1 < 16) {
      stage(t + 1);
      asm volatile("s_waitcnt vmcnt(4)" ::: "memory");
    } else {
      asm volatile("s_waitcnt vmcnt(0)" ::: "memory");
    }
    __builtin_amdgcn_s_barrier();
    MEMFENCE;
    const uint16_t* Kbp = &Kb[t & 1][0];
    const uint16_t* Vbp = &Vb[t & 1][0];

    // S^T[k][q] = mfma(K, Q); lane = q, regs = k
    f32x16 st[2];
    __builtin_amdgcn_s_setprio(1);
#pragma unroll
    for (int kblk = 0; kblk < 2; ++kblk) {
      f32x16 acc = {};
      const uint16_t* kr = Kbp + (kblk * 32 + l31) * 64;
#pragma unroll
      for (int dblk = 0; dblk < 4; ++dblk) {
        bf16x8 kf = ldb8(kr + ((dblk * 2 + hh) ^ (l31 & 7)) * 8);
        acc = __builtin_amdgcn_mfma_f32_32x32x16_bf16(kf, qa[dblk], acc, 0, 0, 0);
      }
      st[kblk] = acc;
    }
    __builtin_amdgcn_s_setprio(0);

    // P = exp2(s - 16), pack to bf16 pairs (v_cvt_pk path) — no max, no branch
    uint32_t pk[2][8];
#pragma unroll
    for (int kblk = 0; kblk < 2; ++kblk)
#pragma unroll
      for (int wn = 0; wn < 8; ++wn) {
        float e0 = exp2f(st[kblk][2 * wn] - MCONST);
        float e1 = exp2f(st[kblk][2 * wn + 1] - MCONST);
        bf16x2 pr = {(__bf16)e0, (__bf16)e1};
        pk[kblk][wn] = __builtin_bit_cast(uint32_t, pr);
      }

    // gather PV A-frags
    bf16x8 af[4];
#pragma unroll
    for (int kb16 = 0; kb16 < 4; ++kb16) {
      const int kblk = kb16 >> 1;
      const int a4 = (kb16 & 1) * 4;
      uint32_t ow0 = hh ? pk[kblk][a4 + 2] : pk[kblk][a4 + 0];
      uint32_t ow1 = hh ? pk[kblk][a4 + 3] : pk[kblk][a4 + 1];
      uint32_t gv0 = hh ? pk[kblk][a4 + 0] : pk[kblk][a4 + 2];
      uint32_t gv1 = hh ? pk[kblk][a4 + 1] : pk[kblk][a4 + 3];
      uint32_t sw0 = (uint32_t)__shfl_xor((int)gv0, 32);
      uint32_t sw1 = (uint32_t)__shfl_xor((int)gv1, 32);
      u32x4 afu;
      afu[0] = hh ? sw0 : ow0;
      afu[1] = hh ? sw1 : ow1;
      afu[2] = hh ? ow0 : sw0;
      afu[3] = hh ? ow1 : sw1;
      af[kb16] = __builtin_bit_cast(bf16x8, afu);
    }

    __builtin_amdgcn_s_setprio(1);
#pragma unroll
    for (int dblk = 0; dblk < 2; ++dblk) {
      const uint16_t* vr = Vbp + (dblk * 32 + l31) * 64;
#pragma unroll
      for (int kb16 = 0; kb16 < 4; ++kb16) {
        bf16x8 vf = ldb8(vr + ((kb16 * 2 + hh) ^ (l31 & 7)) * 8);
        oacc[dblk] = __builtin_amdgcn_mfma_f32_32x32x16_bf16(af[kb16], vf, oacc[dblk], 0, 0, 0);
      }
    }
#pragma unroll
    for (int kb16 = 0; kb16 < 4; ++kb16)   // row-sum on matrix pipe
      lacc = __builtin_amdgcn_mfma_f32_32x32x16_bf16(af[kb16], ones, lacc, 0, 0, 0);
    __builtin_amdgcn_s_setprio(0);
    MEMFENCE;
    __builtin_amdgcn_s_barrier();
  }

  // one-time masked-key correction: each masked key contributed exactly 2^-16
  int cnt = 0;
#pragma unroll
  for (int it = 0; it < 16; ++it) cnt += 64 - __popcll(mbits[it]);
  const float cntf = (float)cnt * PMASKED;

  // write unnormalized partial O (bf16)
  uint16_t* ob = po + ((size_t)z * PROWS + (size_t)bh * NSEQ + q0) * 64;
#pragma unroll
  for (int r = 0; r < 16; ++r) {
    const int qrow = (r & 3) + 8 * (r >> 2) + 4 * hh;
#pragma unroll
    for (int dblk = 0; dblk < 2; ++dblk)
      ob[(size_t)qrow * 64 + dblk * 32 + l31] = f2bf(oacc[dblk][r]);
  }
  // write denom per q-row (lane 0 of each half holds the row-sum in lacc)
  if (l31 == 0) {
#pragma unroll
    for (int r = 0; r < 16; ++r) {
      const int qrow = (r & 3) + 8 * (r >> 2) + 4 * hh;
      pml[(size_t)z * PROWS + (size_t)bh * NSEQ + q0 + qrow] = lacc[r] - cntf;
    }
  }
}

// ---------------- merge split-KV partials -> o_bf ------------------------------
// Constant max on both halves -> O = (po1 + po2) / (d1 + d2).
__global__ __launch_bounds__(256) void merge_kernel(const uint16_t* __restrict__ po,
                                                    const float* __restrict__ pml,
                                                    uint16_t* __restrict__ o) {
  int gid = blockIdx.x * 256 + threadIdx.x;   // 393216 = 49152 rows x 8 chunks
  int row = gid >> 3;
  int c0 = (gid & 7) * 8;
  float L = pml[row] + pml[PROWS + row];
  float inv = L > 0.f ? 1.f / L : 0.f;
  u16x8 a = *reinterpret_cast<const u16x8*>(po + (size_t)row * 64 + c0);
  u16x8 b = *reinterpret_cast<const u16x8*>(po + ((size_t)PROWS + row) * 64 + c0);
  int bh = row >> 11, q = row & 2047;
  int bb = bh / NHEAD, hh = bh % NHEAD;
  uint16_t* op = o + ((size_t)(bb * NSEQ + q) * DMODEL + hh * HDIM + c0);
  u16x8 outv;
#pragma unroll
  for (int e = 0; e < 8; ++e)
    outv[e] = f2bf((bf2f(a[e]) + bf2f(b[e])) * inv);
  *reinterpret_cast<u16x8*>(op) = outv;
}

// ---------------- host ----------------
extern "C" void kernel_launch(void* const* d_in, const int* in_sizes, int n_in,
                              void* d_out, int out_size, void* d_ws, size_t ws_size,
                              hipStream_t stream) {
  const float* x      = (const float*)d_in[0];
  const int*   amask  = (const int*)d_in[1];
  const float* ln1_g  = (const float*)d_in[2];
  const float* ln1_b  = (const float*)d_in[3];
  const float* qkv_w  = (const float*)d_in[4];
  const float* q_bias = (const float*)d_in[5];
  const float* v_bias = (const float*)d_in[6];
  const float* proj_w = (const float*)d_in[7];
  const float* proj_b = (const float*)d_in[8];
  const float* ln2_g  = (const float*)d_in[9];
  const float* ln2_b  = (const float*)d_in[10];
  const float* fc1_w  = (const float*)d_in[11];
  const float* fc1_b  = (const float*)d_in[12];
  const float* fc2_w  = (const float*)d_in[13];
  const float* fc2_b  = (const float*)d_in[14];
  const float* g1     = (const float*)d_in[15];
  const float* g2     = (const float*)d_in[16];

  char* ws = (char*)d_ws;
  uint16_t* qkvw_bf  = (uint16_t*)(ws + 0);
  uint16_t* projw_bf = (uint16_t*)(ws + 3538944);
  uint16_t* fc1w_bf  = (uint16_t*)(ws + 4718592);
  uint16_t* fc2w_bf  = (uint16_t*)(ws + 9437184);
  float*    qkvbias  = (float*)(ws + 14155776);
  uint16_t* h_bf     = (uint16_t*)(ws + 14164992);
  uint16_t* km       = h_bf;                         // masked-K alias
  uint16_t* h2_bf    = h_bf;                         // ln2 out (after attn)
  uint16_t* qkv_bf   = (uint16_t*)(ws + 20456448);
  uint16_t* vt_bf    = (uint16_t*)(ws + 39330816);
  uint16_t* o_bf     = (uint16_t*)(ws + 45622272);
  float*    x1_f     = (float*)(ws + 51913728);
  uint16_t* po       = (uint16_t*)(ws + 51913728);   // partials alias x1_f
  float*    pml      = (float*)(ws + 64496640);      // 2*PROWS floats (393 KB)
  uint16_t* fc1_bf   = qkv_bf;

  const int M = BATCH * NSEQ;

  cvt4_kernel<<<(N_QKVW + N_PROJW + N_FC1W + N_FC2W) / 1024, 256, 0, stream>>>(
      qkv_w, proj_w, fc1_w, fc2_w, qkvw_bf, projw_bf, fc1w_bf, fc2w_bf);
  bias_kernel<<<(3 * DMODEL + 255) / 256, 256, 0, stream>>>(q_bias, v_bias, qkvbias);

  ln_kernel<<<M, 256, 0, stream>>>(x, ln1_g, ln1_b, h_bf);
  gemm128<0><<<dim3((3 * DMODEL) / 128, M / 128), 256, 0, stream>>>(
      h_bf, qkvw_bf, qkvbias, qkv_bf, M, 3 * DMODEL, DMODEL);
  prep_kernel<<<dim3(BATCH * NHEAD, NSEQ / 64), 256, 0, stream>>>(qkv_bf, amask, km, vt_bf);
  attn_kernel<<<dim3(BATCH * NHEAD, NSEQ / 128, 2), 256, 0, stream>>>(
      qkv_bf, km, vt_bf, amask, po, pml);
  merge_kernel<<<(PROWS * 8) / 256, 256, 0, stream>>>(po, pml, o_bf);
  gemm64<<<dim3(DMODEL / 64, M / 64), 256, 0, stream>>>(
      o_bf, projw_bf, proj_b, x1_f, x, g1, M, DMODEL, DMODEL);
  ln_kernel<<<M, 256, 0, stream>>>(x1_f, ln2_g, ln2_b, h2_bf);
  gemm128<2><<<dim3(HIDDEN / 128, M / 128), 256, 0, stream>>>(
      h2_bf, fc1w_bf, fc1_b, fc1_bf, M, HIDDEN, DMODEL);
  gemm64<<<dim3(DMODEL / 64, M / 64), 256, 0, stream>>>(
      fc1_bf, fc2w_bf, fc2_b, (float*)d_out, x1_f, g2, M, DMODEL, HIDDEN);
}